// Round 5
// baseline (360.700 us; speedup 1.0000x reference)
//
#include <hip/hip_runtime.h>
#include <hip/hip_bf16.h>
#include <math.h>

#define BB 2
#define SS 1024
#define HH 2048
#define NHD 16
#define NOPE 128
#define ROPED 64
#define VDIM 128
#define QKD 192
#define QLR 1536
#define KVLR 512
#define EPSF 1e-5f
#define NCOMB 2176   // QLR + 576 kv + 64 pad

typedef __bf16 bf16x8 __attribute__((ext_vector_type(8)));
typedef float  f32x4  __attribute__((ext_vector_type(4)));

__device__ __forceinline__ void gload_lds16(const __bf16* g, __bf16* l) {
    __builtin_amdgcn_global_load_lds(
        (const __attribute__((address_space(1))) void*)g,
        (__attribute__((address_space(3))) void*)l, 16, 0, 0);
}

// ---------------------------------------------------------------------------
// Ring-buffered 1-barrier GEMM core, 128x128 tile, BK=32, NB buffers.
//   NB=3: 48 KB LDS (3 blocks/CU) — IDENTICAL schedule to R4's proven tri.
//   NB=5: 80 KB LDS (2 blocks/CU) — issue-to-admit depth 3 iters (~450cy)
//         at the same 1-barrier-per-16-MFMA rate; for low-occupancy dense.
//   Race screen (R3/R4, generalized): stage at iter t targets the buffer of
//   tile t-1 (reads done before barrier(t-1)); counted vmcnt admits tile t+1
//   with up to NB-2 tiles still in flight (in-order vmcnt, m135); a buffer
//   is re-staged NB iters after staging, loads long retired; each wave
//   rewrites only its own slice. One barrier per iter, wave-uniform count.
//   XOR swizzle on 16B chunks: chunk ^= (row>>1)&3 (2-way = free), applied
//   to pre-swizzled GLOBAL source + ds_read addresses (both-sides, R1/R2).
// ---------------------------------------------------------------------------
template<int BK, int NB>
__device__ __forceinline__ void gemm_core_ring(
    const __bf16* __restrict__ Ab, const __bf16* __restrict__ Bb,
    int lda, int ldb, int m0, int n0, int K, __bf16* lds, f32x4 acc[4][4])
{
    static_assert(BK == 32, "ring core tuned for BK=32 (vmcnt steps of 4)");
    constexpr int CH    = BK / 8;      // 16B chunks per row = loads/thread/tile
    constexpr int LPT   = CH / 2;
    constexpr int BUFE  = 256 * BK;
    constexpr int BOFF  = 128 * BK;
    constexpr int RSTEP = 2048 / BK;
    const int tid = threadIdx.x;
    const int w = tid >> 6, lane = tid & 63, quad = lane >> 4, ln = lane & 15;
    const int wm = (w >> 1) * 64, wn = (w & 1) * 64;
    const int nt = K / BK;

    const int sr  = tid / CH;
    const int spc = tid % CH;
    const int sc  = spc ^ ((sr >> 1) & 3);
    const __bf16* gA = Ab + (size_t)(m0 + sr) * lda + sc * 8;
    const __bf16* gB = Bb + (size_t)(n0 + sr) * ldb + sc * 8;

    const int swm = ((wm + ln) >> 1) & 3;
    const int swn = ((wn + ln) >> 1) & 3;

    auto stage = [&](__bf16* base, int kk) {
        __bf16* la = base + w * 512;
        __bf16* lb = la + BOFF;
        const __bf16* ga = gA + kk;
        const __bf16* gb = gB + kk;
#pragma unroll
        for (int i = 0; i < LPT; ++i) {
            gload_lds16(ga + (size_t)(i * RSTEP) * lda, la + i * 2048);
            gload_lds16(gb + (size_t)(i * RSTEP) * ldb, lb + i * 2048);
        }
    };

    // prologue: stage tiles 0..min(NB-1,nt)-1, admit tile 0
#pragma unroll
    for (int j = 0; j < NB - 1; ++j)
        if (j < nt) stage(lds + j * BUFE, j * BK);
    {
        int P = (nt < NB - 1) ? nt : NB - 1;
        switch (P - 1) {
            case 0: asm volatile("s_waitcnt vmcnt(0)" ::: "memory"); break;
            case 1: asm volatile("s_waitcnt vmcnt(4)" ::: "memory"); break;
            case 2: asm volatile("s_waitcnt vmcnt(8)" ::: "memory"); break;
            default: asm volatile("s_waitcnt vmcnt(12)" ::: "memory"); break;
        }
    }
    __builtin_amdgcn_s_barrier();
    __builtin_amdgcn_sched_barrier(0);

    int cur = 0;
    for (int t = 0; t < nt; ++t) {
        __bf16* p0 = lds + cur * BUFE;
        bf16x8 af[4], bv[4];
#pragma unroll
        for (int i = 0; i < 4; ++i) {
            af[i] = *(const bf16x8*)
                &p0[(wm + ln) * BK + i * 16 * BK + ((quad ^ swm) << 3)];
            bv[i] = *(const bf16x8*)
                &p0[BOFF + (wn + ln) * BK + i * 16 * BK + ((quad ^ swn) << 3)];
        }
        if (t + NB - 1 < nt) {
            int stg = cur - 1; if (stg < 0) stg = NB - 1;
            stage(lds + stg * BUFE, (t + NB - 1) * BK);
        }
        asm volatile("s_waitcnt lgkmcnt(0)" ::: "memory");
        __builtin_amdgcn_sched_barrier(0);
        __builtin_amdgcn_s_setprio(1);
#pragma unroll
        for (int mi = 0; mi < 4; ++mi)
#pragma unroll
            for (int ni = 0; ni < 4; ++ni)
                acc[mi][ni] = __builtin_amdgcn_mfma_f32_16x16x32_bf16(
                    af[mi], bv[ni], acc[mi][ni], 0, 0, 0);
        __builtin_amdgcn_s_setprio(0);
        if (t + 1 < nt) {
            __builtin_amdgcn_sched_barrier(0);
            int issued_max = t + NB - 1; if (issued_max > nt - 1) issued_max = nt - 1;
            int infl = issued_max - (t + 1);     // tiles in flight beyond t+1
            switch (infl) {
                case 0: asm volatile("s_waitcnt vmcnt(0)" ::: "memory"); break;
                case 1: asm volatile("s_waitcnt vmcnt(4)" ::: "memory"); break;
                case 2: asm volatile("s_waitcnt vmcnt(8)" ::: "memory"); break;
                default: asm volatile("s_waitcnt vmcnt(12)" ::: "memory"); break;
            }
            __builtin_amdgcn_s_barrier();        // single barrier per tile
            __builtin_amdgcn_sched_barrier(0);
        }
        cur = cur + 1; if (cur == NB) cur = 0;
    }
}

// ---------------------------------------------------------------------------
// MFMA bf16 GEMM: C[M,N] = A[M,K] @ B[N,K]^T (batched / split-K via
// blockIdx.z with element-offset strides sA/sB and output stride sC).
// ---------------------------------------------------------------------------
template<bool OUT_BF16, int MINW, int NB>
__global__ __launch_bounds__(256, MINW) void gemm_mfma(
    const __bf16* __restrict__ A, const __bf16* __restrict__ B, void* __restrict__ Cv,
    int M, int N, int K, int lda, int ldb, int ldc,
    long long sA, long long sB, long long sC)
{
    __shared__ __bf16 lds[NB * 256 * 32];
    const __bf16* Ab = A + (long long)blockIdx.z * sA;
    const __bf16* Bb = B + (long long)blockIdx.z * sB;
    const int tid = threadIdx.x;
    const int w = tid >> 6, lane = tid & 63, quad = lane >> 4, ln = lane & 15;
    const int m0 = blockIdx.y * 128, n0 = blockIdx.x * 128;
    const int wm = (w >> 1) * 64, wn = (w & 1) * 64;

    f32x4 acc[4][4];
#pragma unroll
    for (int i = 0; i < 4; ++i)
#pragma unroll
        for (int j = 0; j < 4; ++j) acc[i][j] = (f32x4){0.f, 0.f, 0.f, 0.f};

    gemm_core_ring<32, NB>(Ab, Bb, lda, ldb, m0, n0, K, lds, acc);

    if (OUT_BF16) {
        __bf16* Cb = (__bf16*)Cv + (long long)blockIdx.z * sC;
#pragma unroll
        for (int mi = 0; mi < 4; ++mi)
#pragma unroll
            for (int r = 0; r < 4; ++r) {
                size_t row = (size_t)(m0 + wm + mi * 16 + quad * 4 + r);
#pragma unroll
                for (int ni = 0; ni < 4; ++ni)
                    Cb[row * ldc + (n0 + wn + ni * 16 + ln)] = (__bf16)acc[mi][ni][r];
            }
    } else {
        float* Cb = (float*)Cv + (long long)blockIdx.z * sC;
#pragma unroll
        for (int mi = 0; mi < 4; ++mi)
#pragma unroll
            for (int r = 0; r < 4; ++r) {
                size_t row = (size_t)(m0 + wm + mi * 16 + quad * 4 + r);
#pragma unroll
                for (int ni = 0; ni < 4; ++ni)
                    Cb[row * ldc + (n0 + wn + ni * 16 + ln)] = acc[mi][ni][r];
            }
    }
}

// ---------------------------------------------------------------------------
// qlat GEMM with fused Qc scatter: Qc[b][h][s][0..512) = q_nope[h] @ Wk[h]^T
// ---------------------------------------------------------------------------
__global__ __launch_bounds__(256, 3) void gemm_qlat(
    const __bf16* __restrict__ qb, const __bf16* __restrict__ Wkb,
    __bf16* __restrict__ Qc)
{
    __shared__ __bf16 lds[3 * 256 * 32];
    const int h = blockIdx.z;
    const __bf16* Ab = qb + (size_t)h * QKD;
    const __bf16* Bb = Wkb + (size_t)h * KVLR * NOPE;
    const int tid = threadIdx.x;
    const int w = tid >> 6, lane = tid & 63, quad = lane >> 4, ln = lane & 15;
    const int m0 = blockIdx.y * 128, n0 = blockIdx.x * 128;
    const int wm = (w >> 1) * 64, wn = (w & 1) * 64;

    f32x4 acc[4][4];
#pragma unroll
    for (int i = 0; i < 4; ++i)
#pragma unroll
        for (int j = 0; j < 4; ++j) acc[i][j] = (f32x4){0.f, 0.f, 0.f, 0.f};

    gemm_core_ring<32, 3>(Ab, Bb, NHD * QKD, NOPE, m0, n0, NOPE, lds, acc);

#pragma unroll
    for (int mi = 0; mi < 4; ++mi)
#pragma unroll
        for (int r = 0; r < 4; ++r) {
            int row = m0 + wm + mi * 16 + quad * 4 + r;   // b*S + s
            int bb = row >> 10, s = row & 1023;
            __bf16* dst = Qc + ((size_t)(bb * NHD + h) * SS + s) * 576;
#pragma unroll
            for (int ni = 0; ni < 4; ++ni)
                dst[n0 + wn + ni * 16 + ln] = (__bf16)acc[mi][ni][r];
        }
}

// ---------------------------------------------------------------------------
// Causal scores GEMM, exact-triangle grid + chunked XCD swizzle.
// ---------------------------------------------------------------------------
__global__ __launch_bounds__(256, 3) void gemm_scores(
    const __bf16* __restrict__ Qc, const __bf16* __restrict__ Kc,
    __bf16* __restrict__ Sc)
{
    int lin = blockIdx.x + 36 * blockIdx.y;          // 0..1151
    lin = (lin & 7) * 144 + (lin >> 3);              // bijective chunk swizzle
    const int z = lin / 36;
    const int i = lin - z * 36;
    int mt = (int)((sqrtf(8.f * i + 1.f) - 1.f) * 0.5f);
    if (mt * (mt + 1) / 2 > i) --mt;
    if ((mt + 1) * (mt + 2) / 2 <= i) ++mt;
    const int nt = i - mt * (mt + 1) / 2;

    const int b = z >> 4;
    __shared__ __bf16 lds[3 * 256 * 32];
    const __bf16* Ab = Qc + (size_t)z * SS * 576;
    const __bf16* Bb = Kc + (size_t)b * SS * 576;
    __bf16* Cb = Sc + (size_t)z * SS * SS;
    const int tid = threadIdx.x;
    const int w = tid >> 6, lane = tid & 63, quad = lane >> 4, ln = lane & 15;
    const int m0 = mt * 128, n0 = nt * 128;
    const int wm = (w >> 1) * 64, wn = (w & 1) * 64;

    f32x4 acc[4][4];
#pragma unroll
    for (int i2 = 0; i2 < 4; ++i2)
#pragma unroll
        for (int j = 0; j < 4; ++j) acc[i2][j] = (f32x4){0.f, 0.f, 0.f, 0.f};

    gemm_core_ring<32, 3>(Ab, Bb, 576, 576, m0, n0, 576, lds, acc);

    const float SCL2 = 0.07216878364870323f * 1.4426950408889634f;  // scale*log2e
#pragma unroll
    for (int mi = 0; mi < 4; ++mi)
#pragma unroll
        for (int r = 0; r < 4; ++r) {
            int row = m0 + wm + mi * 16 + quad * 4 + r;
#pragma unroll
            for (int ni = 0; ni < 4; ++ni) {
                int col = n0 + wn + ni * 16 + ln;
                float v = acc[mi][ni][r] * SCL2;
                if (col > row) v = -1e30f;
                Cb[(size_t)row * SS + col] = (__bf16)v;
            }
        }
}

// ---------------------------------------------------------------------------
// Row softmax (exp2 domain). One wave per row, shfl-only reductions.
// ---------------------------------------------------------------------------
__global__ __launch_bounds__(256) void softmax_kernel(__bf16* __restrict__ Sc)
{
    const int z = blockIdx.y;
    const int w = threadIdx.x >> 6, lane = threadIdx.x & 63;
    const int r = blockIdx.x * 4 + w;
    __bf16* row = Sc + (size_t)z * SS * SS + (size_t)r * SS;
    const int ncols = ((r >> 7) + 1) << 7;
    const int i0 = lane * 8, i1 = i0 + 512;
    const bool a0 = i0 < ncols, a1 = i1 < ncols;
    float v[16];
    float lmax = -1e30f;
    if (a0) {
        bf16x8 c = *(const bf16x8*)(row + i0);
#pragma unroll
        for (int j = 0; j < 8; ++j) { v[j] = (float)c[j]; lmax = fmaxf(lmax, v[j]); }
    }
    if (a1) {
        bf16x8 c = *(const bf16x8*)(row + i1);
#pragma unroll
        for (int j = 0; j < 8; ++j) { v[8 + j] = (float)c[j]; lmax = fmaxf(lmax, v[8 + j]); }
    }
#pragma unroll
    for (int off = 1; off < 64; off <<= 1) lmax = fmaxf(lmax, __shfl_xor(lmax, off));
    float lsum = 0.f;
    if (a0) {
#pragma unroll
        for (int j = 0; j < 8; ++j) { v[j] = __builtin_amdgcn_exp2f(v[j] - lmax); lsum += v[j]; }
    }
    if (a1) {
#pragma unroll
        for (int j = 0; j < 8; ++j) { v[8 + j] = __builtin_amdgcn_exp2f(v[8 + j] - lmax); lsum += v[8 + j]; }
    }
#pragma unroll
    for (int off = 1; off < 64; off <<= 1) lsum += __shfl_xor(lsum, off);
    const float inv = 1.f / lsum;
    if (a0) {
        bf16x8 c;
#pragma unroll
        for (int j = 0; j < 8; ++j) c[j] = (__bf16)(v[j] * inv);
        *(bf16x8*)(row + i0) = c;
    }
    if (a1) {
        bf16x8 c;
#pragma unroll
        for (int j = 0; j < 8; ++j) c[j] = (__bf16)(v[8 + j] * inv);
        *(bf16x8*)(row + i1) = c;
    }
}

// ---------------------------------------------------------------------------
// PV GEMM with chunked XCD swizzle: grid (32, 32) linear -> (z, mt, nt).
// ---------------------------------------------------------------------------
__global__ __launch_bounds__(256, 3) void gemm_pv(
    const __bf16* __restrict__ Sc, const __bf16* __restrict__ Vt,
    __bf16* __restrict__ ctx)
{
    int lin = blockIdx.x + 32 * blockIdx.y;          // 0..1023
    lin = (lin & 7) * 128 + (lin >> 3);              // bijective chunk swizzle
    const int z = lin >> 5;
    const int rem = lin & 31;
    const int mt = rem >> 2, nt = rem & 3;

    const int b = z >> 4, h = z & 15;
    const int Keff = (mt + 1) * 128;
    __shared__ __bf16 lds[3 * 256 * 32];
    const __bf16* Ab = Sc + (size_t)z * SS * SS;
    const __bf16* Bb = Vt + (size_t)b * 512 * 1024;
    const int tid = threadIdx.x;
    const int w = tid >> 6, lane = tid & 63, quad = lane >> 4, ln = lane & 15;
    const int m0 = mt * 128, n0 = nt * 128;
    const int wm = (w >> 1) * 64, wn = (w & 1) * 64;

    f32x4 acc[4][4];
#pragma unroll
    for (int i = 0; i < 4; ++i)
#pragma unroll
        for (int j = 0; j < 4; ++j) acc[i][j] = (f32x4){0.f, 0.f, 0.f, 0.f};

    gemm_core_ring<32, 3>(Ab, Bb, SS, 1024, m0, n0, Keff, lds, acc);

#pragma unroll
    for (int mi = 0; mi < 4; ++mi)
#pragma unroll
        for (int r = 0; r < 4; ++r) {
            int row = m0 + wm + mi * 16 + quad * 4 + r;
            __bf16* op = ctx + (size_t)(b * SS + row) * (NHD * KVLR) + h * KVLR;
#pragma unroll
            for (int ni = 0; ni < 4; ++ni)
                op[n0 + wn + ni * 16 + ln] = (__bf16)acc[mi][ni][r];
        }
}

// ---------------------------------------------------------------------------
// Cast / reduce helpers
// ---------------------------------------------------------------------------
__global__ __launch_bounds__(256) void castf2b(const float* __restrict__ in,
                                               __bf16* __restrict__ out, int n)
{
    int i = (blockIdx.x * 256 + threadIdx.x) * 4;
    if (i < n) {
        float4 v = *(const float4*)(in + i);
        out[i] = (__bf16)v.x; out[i + 1] = (__bf16)v.y;
        out[i + 2] = (__bf16)v.z; out[i + 3] = (__bf16)v.w;
    }
}

// out = a + b (fp32, vectorized) — split-K reduce for the final GEMM.
__global__ __launch_bounds__(256) void reduce2(const float* __restrict__ a,
                                               const float* __restrict__ b,
                                               float* __restrict__ o, int n)
{
    int i = (blockIdx.x * 256 + threadIdx.x) * 4;
    if (i < n) {
        float4 x = *(const float4*)(a + i);
        float4 y = *(const float4*)(b + i);
        x.x += y.x; x.y += y.y; x.z += y.z; x.w += y.w;
        *(float4*)(o + i) = x;
    }
}

// combined [w_qa(1536); w_kva(576); pad(64)] x 2048 -> bf16
__global__ __launch_bounds__(256) void cast_comb(const float* __restrict__ wqa,
                                                 const float* __restrict__ wkva,
                                                 __bf16* __restrict__ out)
{
    int idx = (blockIdx.x * 256 + threadIdx.x) * 4;
    int row = idx >> 11, col = idx & 2047;
    const float* src;
    if (row < 1536)      src = wqa + (size_t)row * 2048 + col;
    else if (row < 2112) src = wkva + (size_t)(row - 1536) * 2048 + col;
    else {
        out[idx] = (__bf16)0.f; out[idx + 1] = (__bf16)0.f;
        out[idx + 2] = (__bf16)0.f; out[idx + 3] = (__bf16)0.f;
        return;
    }
    float4 v = *(const float4*)src;
    out[idx] = (__bf16)v.x; out[idx + 1] = (__bf16)v.y;
    out[idx + 2] = (__bf16)v.z; out[idx + 3] = (__bf16)v.w;
}

// batched transpose-cast: in[z][R][C] fp32 -> out[z][C][R] bf16
__global__ __launch_bounds__(256) void transpose_cast(const float* __restrict__ in,
                                                      __bf16* __restrict__ out,
                                                      int R, int C)
{
    __shared__ float t[32][33];
    in  += (size_t)blockIdx.z * R * C;
    out += (size_t)blockIdx.z * R * C;
    int c0 = blockIdx.x * 32, r0 = blockIdx.y * 32;
    int tx = threadIdx.x & 31, ty = threadIdx.x >> 5;
#pragma unroll
    for (int i = 0; i < 4; ++i) {
        int r = ty + i * 8;
        t[r][tx] = in[(size_t)(r0 + r) * C + c0 + tx];
    }
    __syncthreads();
#pragma unroll
    for (int i = 0; i < 4; ++i) {
        int rr = ty + i * 8;
        out[(size_t)(c0 + rr) * R + r0 + tx] = (__bf16)t[tx][rr];
    }
}

// Kc[b][k][f<512] bf16 -> Vt[b][f][k] bf16 (key-contiguous V)
__global__ __launch_bounds__(256) void transpose_kc(const __bf16* __restrict__ Kc,
                                                    __bf16* __restrict__ Vt)
{
    __shared__ __bf16 t[32][33];
    int b = blockIdx.z;
    int k0 = blockIdx.x * 32, f0 = blockIdx.y * 32;
    int tx = threadIdx.x & 31, ty = threadIdx.x >> 5;   // ty 0..7
    const __bf16* src = Kc + (size_t)b * SS * 576;
#pragma unroll
    for (int i = 0; i < 4; ++i)
        t[ty + i * 8][tx] = src[(size_t)(k0 + ty + i * 8) * 576 + f0 + tx];
    __syncthreads();
    __bf16* dst = Vt + (size_t)b * 512 * 1024;
#pragma unroll
    for (int i = 0; i < 4; ++i)
        dst[(size_t)(f0 + ty + i * 8) * 1024 + k0 + tx] = t[tx][ty + i * 8];
}

// ---------------------------------------------------------------------------
// LayerNorm over (x1+x2) fp32 (row stride ldx, split-K partials) -> bf16.
// ---------------------------------------------------------------------------
__global__ __launch_bounds__(256) void ln_kernel(const float* __restrict__ x,
                                                 const float* __restrict__ x2,
                                                 const float* __restrict__ w,
                                                 __bf16* __restrict__ y, int N, int ldx)
{
    long long row = blockIdx.x;
    const float* xr  = x  + row * ldx;
    const float* x2r = x2 + row * ldx;
    __bf16* yr = y + row * N;
    int tid = threadIdx.x;
    float s = 0.f, ss = 0.f;
    for (int i = tid; i < N; i += 256) {
        float v = xr[i] + x2r[i]; s += v; ss += v * v;
    }
#pragma unroll
    for (int off = 32; off > 0; off >>= 1) { s += __shfl_down(s, off); ss += __shfl_down(ss, off); }
    __shared__ float rs[4], rss[4];
    __shared__ float smean, sinv;
    int wave = tid >> 6, lane = tid & 63;
    if (lane == 0) { rs[wave] = s; rss[wave] = ss; }
    __syncthreads();
    if (tid == 0) {
        float S = rs[0] + rs[1] + rs[2] + rs[3];
        float Q = rss[0] + rss[1] + rss[2] + rss[3];
        float mean = S / N;
        float var = Q / N - mean * mean;
        smean = mean; sinv = rsqrtf(var + EPSF);
    }
    __syncthreads();
    float mean = smean, inv = sinv;
    for (int i = tid; i < N; i += 256)
        yr[i] = (__bf16)(((xr[i] + x2r[i]) - mean) * inv * w[i]);
}

// ---------------------------------------------------------------------------
// Per-token prep over (kva+kva2) split-K partials: Kc row + roped q_pe -> Qc.
// ---------------------------------------------------------------------------
__global__ __launch_bounds__(256) void prep_kernel(
    const float* __restrict__ kva, const float* __restrict__ kva2, int ld,
    const float* __restrict__ kvw,
    const float* __restrict__ cosb, const float* __restrict__ sinb,
    __bf16* __restrict__ Kc, const __bf16* __restrict__ q,
    __bf16* __restrict__ Qc)
{
    long long row = blockIdx.x;
    const float* kr  = kva  + row * ld;
    const float* k2r = kva2 + row * ld;
    const float* cr = cosb + row * ROPED;
    const float* sr = sinb + row * ROPED;
    int tid = threadIdx.x;
    float v0 = kr[tid] + k2r[tid], v1 = kr[tid + 256] + k2r[tid + 256];
    float s = v0 + v1, ss = v0 * v0 + v1 * v1;
#pragma unroll
    for (int off = 32; off > 0; off >>= 1) { s += __shfl_down(s, off); ss += __shfl_down(ss, off); }
    __shared__ float rs[4], rss[4];
    __shared__ float smean, sinv;
    int wave = tid >> 6, lane = tid & 63;
    if (lane == 0) { rs[wave] = s; rss[wave] = ss; }
    __syncthreads();
    if (tid == 0) {
        float S = rs[0] + rs[1] + rs[2] + rs[3];
        float Q = rss[0] + rss[1] + rss[2] + rss[3];
        float mean = S / KVLR;
        float var = Q / KVLR - mean * mean;
        smean = mean; sinv = rsqrtf(var + EPSF);
    }
    __syncthreads();
    float mean = smean, inv = sinv;
    __bf16* kc = Kc + row * 576;
    kc[tid]       = (__bf16)((v0 - mean) * inv * kvw[tid]);
    kc[tid + 256] = (__bf16)((v1 - mean) * inv * kvw[tid + 256]);
    if (tid < 32) {
        float x1 = kr[KVLR + tid] + k2r[KVLR + tid];
        float x2 = kr[KVLR + 32 + tid] + k2r[KVLR + 32 + tid];
        kc[512 + tid]      = (__bf16)(x1 * cr[tid] - x2 * sr[tid]);
        kc[512 + 32 + tid] = (__bf16)(x2 * cr[32 + tid] + x1 * sr[32 + tid]);
    }
    const int bb = (int)(row >> 10), sp = (int)(row & 1023);
    const __bf16* qr = q + row * (NHD * QKD);
#pragma unroll
    for (int j = 0; j < 2; ++j) {
        int idx = tid + j * 256;
        int h = idx >> 5, p = idx & 31;
        const __bf16* base = qr + h * QKD + NOPE;
        float x1 = (float)base[p], x2 = (float)base[32 + p];
        __bf16* qcb = Qc + ((size_t)(bb * NHD + h) * SS + sp) * 576 + 512;
        qcb[p]      = (__bf16)(x1 * cr[p] - x2 * sr[p]);
        qcb[32 + p] = (__bf16)(x2 * cr[32 + p] + x1 * sr[32 + p]);
    }
}

// ---------------------------------------------------------------------------
extern "C" void kernel_launch(void* const* d_in, const int* in_sizes, int n_in,
                              void* d_out, int out_size, void* d_ws, size_t ws_size,
                              hipStream_t stream)
{
    const float* hidden    = (const float*)d_in[0];
    const float* cosb      = (const float*)d_in[1];
    const float* sinb      = (const float*)d_in[2];
    const float* w_qa      = (const float*)d_in[3];
    const float* q_a_ln_w  = (const float*)d_in[4];
    const float* w_qb      = (const float*)d_in[5];
    const float* w_kva     = (const float*)d_in[6];
    const float* kv_a_ln_w = (const float*)d_in[7];
    const float* W_UK_T    = (const float*)d_in[8];
    const float* W_UV      = (const float*)d_in[9];
    const float* w_o       = (const float*)d_in[10];
    float* out = (float*)d_out;

    const int M = BB * SS;  // 2048
    // ---- HEAD region: transient buffers, later aliased by Sc (67.1 MB) ----
    float*  qakva = (float*)d_ws;
    __bf16* Xb    = (__bf16*)(qakva + (size_t)M * NCOMB);
    __bf16* qab   = Xb    + (size_t)M * HH;
    __bf16* qb    = qab   + (size_t)M * QLR;
    __bf16* qlatb = qb    + (size_t)M * NHD * QKD;   // 33.6MB slot: gemm1 part1
    float*  part1 = (float*)qlatb;                    // 17.8MB used
    __bf16* Sc    = (__bf16*)d_ws;                    // aliases head after qlat
    // ---- TAIL region: persistent ----
    __bf16* Kc    = qlatb + (size_t)M * NHD * KVLR;   // M*576
    __bf16* Qc    = Kc    + (size_t)M * 576;          // M*9216
    __bf16* Vt    = Qc    + (size_t)M * NHD * 576;    // 2*512*1024
    __bf16* ctxb  = Vt    + (size_t)BB * 512 * SS;    // M*8192
    __bf16* ohb   = ctxb  + (size_t)M * NHD * KVLR;   // M*2048
    __bf16* w_cmb = ohb   + (size_t)M * HH;           // 2176*2048
    __bf16* w_qbb = w_cmb + (size_t)NCOMB * HH;       // 3072*1536
    __bf16* Wkb   = w_qbb + (size_t)NHD * QKD * QLR;  // 16*512*128
    __bf16* Wvb   = Wkb   + (size_t)NHD * KVLR * NOPE;// 16*128*512
    __bf16* w_ob  = Wvb   + (size_t)NHD * VDIM * KVLR;// 2048*2048

    dim3 blk(256);

    // --- casts ---
    castf2b<<<dim3((M * HH) / 1024), blk, 0, stream>>>(hidden, Xb, M * HH);
    cast_comb<<<dim3((NCOMB * HH) / 1024), blk, 0, stream>>>(w_qa, w_kva, w_cmb);
    castf2b<<<dim3((NHD * QKD * QLR) / 1024), blk, 0, stream>>>(w_qb, w_qbb, NHD * QKD * QLR);
    castf2b<<<dim3((HH * HH) / 1024), blk, 0, stream>>>(w_o, w_ob, HH * HH);
    transpose_cast<<<dim3(KVLR / 32, NOPE / 32, NHD), blk, 0, stream>>>(W_UK_T, Wkb, NOPE, KVLR);
    transpose_cast<<<dim3(VDIM / 32, KVLR / 32, NHD), blk, 0, stream>>>(W_UV, Wvb, KVLR, VDIM);

    // 1+4 fused, split-K=2: part_s = Xb[:, s*1024:] @ w_cmb[:, s*1024:]^T
    gemm_mfma<false, 2, 5><<<dim3(NCOMB / 128, M / 128, 2), blk, 0, stream>>>(
        Xb, w_cmb, qakva, M, NCOMB, 1024, HH, HH, NCOMB,
        1024, 1024, (long long)(part1 - qakva));
    // 2. qab = bf16(LN(part0+part1 [:, :1536]))
    ln_kernel<<<dim3(M), blk, 0, stream>>>(qakva, part1, q_a_ln_w, qab, QLR, NCOMB);
    // 3. qb = qab @ w_qb^T (bf16), ring-5 deep prefetch
    gemm_mfma<true, 2, 5><<<dim3(NHD * QKD / 128, M / 128, 1), blk, 0, stream>>>(
        qab, w_qbb, qb, M, NHD * QKD, QLR, QLR, QLR, NHD * QKD, 0, 0, 0);
    // 5. Kc = [LN(kv_c), rope(k_pe)] from part0+part1; roped q_pe -> Qc
    prep_kernel<<<dim3(M), blk, 0, stream>>>(qakva + QLR, part1 + QLR, NCOMB,
                                             kv_a_ln_w, cosb, sinb, Kc, qb, Qc);
    // 5b. Vt = transpose(Kc[:, :512])
    transpose_kc<<<dim3(SS / 32, 512 / 32, BB), blk, 0, stream>>>(Kc, Vt);
    // 6. Qc[...,0:512) = q_nope[h] @ Wkb[h]^T
    gemm_qlat<<<dim3(KVLR / 128, M / 128, NHD), blk, 0, stream>>>(qb, Wkb, Qc);
    // 8a. Sc = causal scores, exact triangle grid (1152 blocks)
    gemm_scores<<<dim3(36, 32), blk, 0, stream>>>(Qc, Kc, Sc);
    // 8b. row softmax in place
    softmax_kernel<<<dim3(SS / 4, 32), blk, 0, stream>>>(Sc);
    // 8c. ctx = P @ V (causal k-bound), linear grid + swizzle
    gemm_pv<<<dim3(32, 32), blk, 0, stream>>>(Sc, Vt, ctxb);
    // 9. ohb[h] = ctx[h] @ Wvb[h]^T
    gemm_mfma<true, 3, 3><<<dim3(VDIM / 128, M / 128, NHD), blk, 0, stream>>>(
        ctxb, Wvb, ohb, M, VDIM, KVLR,
        NHD * KVLR, KVLR, NHD * VDIM,
        (long long)KVLR, (long long)VDIM * KVLR, (long long)VDIM);
    // 10. out = ohb @ w_o^T, split-K=2 into Sc region (dead), then reduce
    float* p10 = (float*)d_ws;
    gemm_mfma<false, 2, 5><<<dim3(HH / 128, M / 128, 2), blk, 0, stream>>>(
        ohb, w_ob, p10, M, HH, 1024, NHD * VDIM, HH, HH,
        1024, 1024, (long long)M * HH);
    reduce2<<<dim3((M * HH) / 1024), blk, 0, stream>>>(
        p10, p10 + (size_t)M * HH, out, M * HH);
}

// Round 6
// 331.932 us; speedup vs baseline: 1.0867x; 1.0867x over previous
//
#include <hip/hip_runtime.h>
#include <hip/hip_bf16.h>
#include <math.h>

#define BB 2
#define SS 1024
#define HH 2048
#define NHD 16
#define NOPE 128
#define ROPED 64
#define VDIM 128
#define QKD 192
#define QLR 1536
#define KVLR 512
#define EPSF 1e-5f
#define NCOMB 2176   // QLR + 576 kv + 64 pad

typedef __bf16 bf16x8 __attribute__((ext_vector_type(8)));
typedef float  f32x4  __attribute__((ext_vector_type(4)));

__device__ __forceinline__ void gload_lds16(const __bf16* g, __bf16* l) {
    __builtin_amdgcn_global_load_lds(
        (const __attribute__((address_space(1))) void*)g,
        (__attribute__((address_space(3))) void*)l, 16, 0, 0);
}

// XCD-chunked bijective tile swizzle (T1). Dispatch order lin -> work so each
// XCD (lin%8 under round-robin dispatch) sweeps a CONTIGUOUS work chunk:
// n-tiles fastest over a contiguous m-range -> A-row panel (0.5 MB) is read
// once from HBM then reused from that XCD's L2. Identity when T%8 != 0.
__device__ __forceinline__ void swz2d(int nx, int ny, int& bx, int& by) {
    int T = nx * ny;
    int lin = blockIdx.x + nx * blockIdx.y;
    if ((T & 7) == 0) {
        int q = T >> 3;
        lin = (lin & 7) * q + (lin >> 3);
    }
    bx = lin % nx;
    by = lin / nx;
}

// ---------------------------------------------------------------------------
// Shared swizzle math (R1/R2-verified, both-sides involution on 16B chunks):
//   BK=64: chunk ^= row&7 ; BK=32: chunk ^= (row>>1)&3  (2-way = free).
// ---------------------------------------------------------------------------

// Double-buffered 2-barrier core (R1 schedule, proven): for dense big-K GEMMs.
template<int BK>
__device__ __forceinline__ void gemm_core_dbuf(
    const __bf16* __restrict__ Ab, const __bf16* __restrict__ Bb,
    int lda, int ldb, int m0, int n0, int K, __bf16* lds, f32x4 acc[4][4])
{
    constexpr int CH    = BK / 8;
    constexpr int LPT   = CH / 2;
    constexpr int BUFE  = 256 * BK;
    constexpr int BOFF  = 128 * BK;
    constexpr int RSTEP = 2048 / BK;
    const int tid = threadIdx.x;
    const int w = tid >> 6, lane = tid & 63, quad = lane >> 4, ln = lane & 15;
    const int wm = (w >> 1) * 64, wn = (w & 1) * 64;
    const int nt = K / BK;

    const int sr  = tid / CH;
    const int spc = tid % CH;
    const int sc  = (BK == 64) ? (spc ^ (sr & 7)) : (spc ^ ((sr >> 1) & 3));
    const __bf16* gA = Ab + (size_t)(m0 + sr) * lda + sc * 8;
    const __bf16* gB = Bb + (size_t)(n0 + sr) * ldb + sc * 8;

    const int swm = (BK == 64) ? ((wm + ln) & 7) : (((wm + ln) >> 1) & 3);
    const int swn = (BK == 64) ? ((wn + ln) & 7) : (((wn + ln) >> 1) & 3);

    auto stage = [&](int buf, int kk) {
        __bf16* la = lds + buf * BUFE + w * 512;
        __bf16* lb = la + BOFF;
        const __bf16* ga = gA + kk;
        const __bf16* gb = gB + kk;
#pragma unroll
        for (int i = 0; i < LPT; ++i) {
            gload_lds16(ga + (size_t)(i * RSTEP) * lda, la + i * 2048);
            gload_lds16(gb + (size_t)(i * RSTEP) * ldb, lb + i * 2048);
        }
    };
    auto wait_stage = [&]() {
        if constexpr (BK == 64) asm volatile("s_waitcnt vmcnt(8)" ::: "memory");
        else                    asm volatile("s_waitcnt vmcnt(4)" ::: "memory");
    };

    stage(0, 0);
    stage(1, BK);
    wait_stage();
    __builtin_amdgcn_s_barrier();
    __builtin_amdgcn_sched_barrier(0);

    for (int t = 0; t < nt; ++t) {
        const int cur = t & 1;
        const __bf16* bufA = lds + cur * BUFE;
        const __bf16* bufB = bufA + BOFF;
        bf16x8 af[BK / 32][4], bv[BK / 32][4];
#pragma unroll
        for (int ks = 0; ks < BK / 32; ++ks)
#pragma unroll
            for (int i = 0; i < 4; ++i) {
                af[ks][i] = *(const bf16x8*)
                    &bufA[(wm + ln) * BK + i * 16 * BK + (((ks * 4 + quad) ^ swm) << 3)];
                bv[ks][i] = *(const bf16x8*)
                    &bufB[(wn + ln) * BK + i * 16 * BK + (((ks * 4 + quad) ^ swn) << 3)];
            }
        __builtin_amdgcn_s_setprio(1);
#pragma unroll
        for (int ks = 0; ks < BK / 32; ++ks)
#pragma unroll
            for (int mi = 0; mi < 4; ++mi)
#pragma unroll
                for (int ni = 0; ni < 4; ++ni)
                    acc[mi][ni] = __builtin_amdgcn_mfma_f32_16x16x32_bf16(
                        af[ks][mi], bv[ks][ni], acc[mi][ni], 0, 0, 0);
        __builtin_amdgcn_s_setprio(0);
        if (t + 1 < nt) {
            __builtin_amdgcn_sched_barrier(0);
            asm volatile("" ::: "memory");
            __builtin_amdgcn_s_barrier();          // (a) reads of buf[cur] done
            asm volatile("" ::: "memory");
            if (t + 2 < nt) {
                stage(cur, (t + 2) * BK);
                wait_stage();
            } else {
                asm volatile("s_waitcnt vmcnt(0)" ::: "memory");
            }
            __builtin_amdgcn_s_barrier();          // (b) publish t+1
            __builtin_amdgcn_sched_barrier(0);
        }
    }
}

// ---------------------------------------------------------------------------
// Triple-buffered 1-barrier core (BK=32: 48 KB LDS -> 3 blocks/CU).
//   Race screen (R3/R4): stage at iter t targets the buffer of tile t-1
//   (reads done before barrier(t-1)); counted vmcnt(4) admits tile t+1
//   (in-order, m135); buffer re-staged 3 iters after staging; each wave
//   rewrites only its own slice. One wave-uniform barrier per tile.
// ---------------------------------------------------------------------------
template<int BK>
__device__ __forceinline__ void gemm_core_tri(
    const __bf16* __restrict__ Ab, const __bf16* __restrict__ Bb,
    int lda, int ldb, int m0, int n0, int K, __bf16* lds, f32x4 acc[4][4])
{
    constexpr int CH    = BK / 8;
    constexpr int LPT   = CH / 2;
    constexpr int BUFE  = 256 * BK;
    constexpr int BOFF  = 128 * BK;
    constexpr int RSTEP = 2048 / BK;
    const int tid = threadIdx.x;
    const int w = tid >> 6, lane = tid & 63, quad = lane >> 4, ln = lane & 15;
    const int wm = (w >> 1) * 64, wn = (w & 1) * 64;
    const int nt = K / BK;

    const int sr  = tid / CH;
    const int spc = tid % CH;
    const int sc  = (BK == 64) ? (spc ^ (sr & 7)) : (spc ^ ((sr >> 1) & 3));
    const __bf16* gA = Ab + (size_t)(m0 + sr) * lda + sc * 8;
    const __bf16* gB = Bb + (size_t)(n0 + sr) * ldb + sc * 8;

    const int swm = (BK == 64) ? ((wm + ln) & 7) : (((wm + ln) >> 1) & 3);
    const int swn = (BK == 64) ? ((wn + ln) & 7) : (((wn + ln) >> 1) & 3);

    auto stage = [&](__bf16* base, int kk) {
        __bf16* la = base + w * 512;
        __bf16* lb = la + BOFF;
        const __bf16* ga = gA + kk;
        const __bf16* gb = gB + kk;
#pragma unroll
        for (int i = 0; i < LPT; ++i) {
            gload_lds16(ga + (size_t)(i * RSTEP) * lda, la + i * 2048);
            gload_lds16(gb + (size_t)(i * RSTEP) * ldb, lb + i * 2048);
        }
    };

    __bf16* p0 = lds;               // tile t
    __bf16* p1 = lds + BUFE;        // tile t+1
    __bf16* p2 = lds + 2 * BUFE;    // stage target (tile t+2)

    stage(p0, 0);
    stage(p1, BK);
    if constexpr (BK == 64) asm volatile("s_waitcnt vmcnt(8)" ::: "memory");
    else                    asm volatile("s_waitcnt vmcnt(4)" ::: "memory");
    __builtin_amdgcn_s_barrier();
    __builtin_amdgcn_sched_barrier(0);

    for (int t = 0; t < nt; ++t) {
        bf16x8 af[BK / 32][4], bv[BK / 32][4];
#pragma unroll
        for (int ks = 0; ks < BK / 32; ++ks)
#pragma unroll
            for (int i = 0; i < 4; ++i) {
                af[ks][i] = *(const bf16x8*)
                    &p0[(wm + ln) * BK + i * 16 * BK + (((ks * 4 + quad) ^ swm) << 3)];
                bv[ks][i] = *(const bf16x8*)
                    &p0[BOFF + (wn + ln) * BK + i * 16 * BK + (((ks * 4 + quad) ^ swn) << 3)];
            }
        if (t + 2 < nt) stage(p2, (t + 2) * BK);   // overwrites tile t-1's buf
        asm volatile("s_waitcnt lgkmcnt(0)" ::: "memory");
        __builtin_amdgcn_sched_barrier(0);
        __builtin_amdgcn_s_setprio(1);
#pragma unroll
        for (int ks = 0; ks < BK / 32; ++ks)
#pragma unroll
            for (int mi = 0; mi < 4; ++mi)
#pragma unroll
                for (int ni = 0; ni < 4; ++ni)
                    acc[mi][ni] = __builtin_amdgcn_mfma_f32_16x16x32_bf16(
                        af[ks][mi], bv[ks][ni], acc[mi][ni], 0, 0, 0);
        __builtin_amdgcn_s_setprio(0);
        if (t + 1 < nt) {
            __builtin_amdgcn_sched_barrier(0);
            if (t + 2 < nt) {
                if constexpr (BK == 64) asm volatile("s_waitcnt vmcnt(8)" ::: "memory");
                else                    asm volatile("s_waitcnt vmcnt(4)" ::: "memory");
            } else {
                asm volatile("s_waitcnt vmcnt(0)" ::: "memory");
            }
            __builtin_amdgcn_s_barrier();          // single barrier per tile
            __builtin_amdgcn_sched_barrier(0);
        }
        __bf16* tmp = p0; p0 = p1; p1 = p2; p2 = tmp;
    }
}

// ---------------------------------------------------------------------------
// MFMA bf16 GEMM: C[M,N] = A[M,K] @ B[N,K]^T (batched via blockIdx.z),
// with XCD-chunked tile swizzle.
// ---------------------------------------------------------------------------
template<bool OUT_BF16, int BK, int MINW, bool TRI>
__global__ __launch_bounds__(256, MINW) void gemm_mfma(
    const __bf16* __restrict__ A, const __bf16* __restrict__ B, void* __restrict__ Cv,
    int M, int N, int K, int lda, int ldb, int ldc,
    long long sA, long long sB, long long sC)
{
    __shared__ __bf16 lds[TRI ? 768 * BK : 512 * BK];
    const __bf16* Ab = A + (long long)blockIdx.z * sA;
    const __bf16* Bb = B + (long long)blockIdx.z * sB;
    const int tid = threadIdx.x;
    const int w = tid >> 6, lane = tid & 63, quad = lane >> 4, ln = lane & 15;
    int bx, by; swz2d(gridDim.x, gridDim.y, bx, by);
    const int m0 = by * 128, n0 = bx * 128;
    const int wm = (w >> 1) * 64, wn = (w & 1) * 64;

    f32x4 acc[4][4];
#pragma unroll
    for (int i = 0; i < 4; ++i)
#pragma unroll
        for (int j = 0; j < 4; ++j) acc[i][j] = (f32x4){0.f, 0.f, 0.f, 0.f};

    if (TRI) gemm_core_tri<BK>(Ab, Bb, lda, ldb, m0, n0, K, lds, acc);
    else     gemm_core_dbuf<BK>(Ab, Bb, lda, ldb, m0, n0, K, lds, acc);

    if (OUT_BF16) {
        __bf16* Cb = (__bf16*)Cv + (long long)blockIdx.z * sC;
#pragma unroll
        for (int mi = 0; mi < 4; ++mi)
#pragma unroll
            for (int r = 0; r < 4; ++r) {
                size_t row = (size_t)(m0 + wm + mi * 16 + quad * 4 + r);
#pragma unroll
                for (int ni = 0; ni < 4; ++ni)
                    Cb[row * ldc + (n0 + wn + ni * 16 + ln)] = (__bf16)acc[mi][ni][r];
            }
    } else {
        float* Cb = (float*)Cv + (long long)blockIdx.z * sC;
#pragma unroll
        for (int mi = 0; mi < 4; ++mi)
#pragma unroll
            for (int r = 0; r < 4; ++r) {
                size_t row = (size_t)(m0 + wm + mi * 16 + quad * 4 + r);
#pragma unroll
                for (int ni = 0; ni < 4; ++ni)
                    Cb[row * ldc + (n0 + wn + ni * 16 + ln)] = acc[mi][ni][r];
            }
    }
}

// ---------------------------------------------------------------------------
// qlat GEMM with fused Qc scatter: Qc[b][h][s][0..512) = q_nope[h] @ Wk[h]^T
// ---------------------------------------------------------------------------
__global__ __launch_bounds__(256, 3) void gemm_qlat(
    const __bf16* __restrict__ qb, const __bf16* __restrict__ Wkb,
    __bf16* __restrict__ Qc)
{
    __shared__ __bf16 lds[768 * 32];
    const int h = blockIdx.z;
    const __bf16* Ab = qb + (size_t)h * QKD;
    const __bf16* Bb = Wkb + (size_t)h * KVLR * NOPE;
    const int tid = threadIdx.x;
    const int w = tid >> 6, lane = tid & 63, quad = lane >> 4, ln = lane & 15;
    int bx, by; swz2d(gridDim.x, gridDim.y, bx, by);
    const int m0 = by * 128, n0 = bx * 128;
    const int wm = (w >> 1) * 64, wn = (w & 1) * 64;

    f32x4 acc[4][4];
#pragma unroll
    for (int i = 0; i < 4; ++i)
#pragma unroll
        for (int j = 0; j < 4; ++j) acc[i][j] = (f32x4){0.f, 0.f, 0.f, 0.f};

    gemm_core_tri<32>(Ab, Bb, NHD * QKD, NOPE, m0, n0, NOPE, lds, acc);

#pragma unroll
    for (int mi = 0; mi < 4; ++mi)
#pragma unroll
        for (int r = 0; r < 4; ++r) {
            int row = m0 + wm + mi * 16 + quad * 4 + r;   // b*S + s
            int bb = row >> 10, s = row & 1023;
            __bf16* dst = Qc + ((size_t)(bb * NHD + h) * SS + s) * 576;
#pragma unroll
            for (int ni = 0; ni < 4; ++ni)
                dst[n0 + wn + ni * 16 + ln] = (__bf16)acc[mi][ni][r];
        }
}

// ---------------------------------------------------------------------------
// Causal scores GEMM, exact-triangle grid + chunked XCD swizzle.
// ---------------------------------------------------------------------------
__global__ __launch_bounds__(256, 3) void gemm_scores(
    const __bf16* __restrict__ Qc, const __bf16* __restrict__ Kc,
    __bf16* __restrict__ Sc)
{
    int lin = blockIdx.x + 36 * blockIdx.y;          // 0..1151
    lin = (lin & 7) * 144 + (lin >> 3);              // bijective chunk swizzle
    const int z = lin / 36;
    const int i = lin - z * 36;
    int mt = (int)((sqrtf(8.f * i + 1.f) - 1.f) * 0.5f);
    if (mt * (mt + 1) / 2 > i) --mt;
    if ((mt + 1) * (mt + 2) / 2 <= i) ++mt;
    const int nt = i - mt * (mt + 1) / 2;

    const int b = z >> 4;
    __shared__ __bf16 lds[768 * 32];
    const __bf16* Ab = Qc + (size_t)z * SS * 576;
    const __bf16* Bb = Kc + (size_t)b * SS * 576;
    __bf16* Cb = Sc + (size_t)z * SS * SS;
    const int tid = threadIdx.x;
    const int w = tid >> 6, lane = tid & 63, quad = lane >> 4, ln = lane & 15;
    const int m0 = mt * 128, n0 = nt * 128;
    const int wm = (w >> 1) * 64, wn = (w & 1) * 64;

    f32x4 acc[4][4];
#pragma unroll
    for (int i2 = 0; i2 < 4; ++i2)
#pragma unroll
        for (int j = 0; j < 4; ++j) acc[i2][j] = (f32x4){0.f, 0.f, 0.f, 0.f};

    gemm_core_tri<32>(Ab, Bb, 576, 576, m0, n0, 576, lds, acc);

    const float SCL2 = 0.07216878364870323f * 1.4426950408889634f;  // scale*log2e
#pragma unroll
    for (int mi = 0; mi < 4; ++mi)
#pragma unroll
        for (int r = 0; r < 4; ++r) {
            int row = m0 + wm + mi * 16 + quad * 4 + r;
#pragma unroll
            for (int ni = 0; ni < 4; ++ni) {
                int col = n0 + wn + ni * 16 + ln;
                float v = acc[mi][ni][r] * SCL2;
                if (col > row) v = -1e30f;
                Cb[(size_t)row * SS + col] = (__bf16)v;
            }
        }
}

// ---------------------------------------------------------------------------
// Row softmax (exp2 domain). One wave per row, shfl-only reductions.
// ---------------------------------------------------------------------------
__global__ __launch_bounds__(256) void softmax_kernel(__bf16* __restrict__ Sc)
{
    const int z = blockIdx.y;
    const int w = threadIdx.x >> 6, lane = threadIdx.x & 63;
    const int r = blockIdx.x * 4 + w;
    __bf16* row = Sc + (size_t)z * SS * SS + (size_t)r * SS;
    const int ncols = ((r >> 7) + 1) << 7;
    const int i0 = lane * 8, i1 = i0 + 512;
    const bool a0 = i0 < ncols, a1 = i1 < ncols;
    float v[16];
    float lmax = -1e30f;
    if (a0) {
        bf16x8 c = *(const bf16x8*)(row + i0);
#pragma unroll
        for (int j = 0; j < 8; ++j) { v[j] = (float)c[j]; lmax = fmaxf(lmax, v[j]); }
    }
    if (a1) {
        bf16x8 c = *(const bf16x8*)(row + i1);
#pragma unroll
        for (int j = 0; j < 8; ++j) { v[8 + j] = (float)c[j]; lmax = fmaxf(lmax, v[8 + j]); }
    }
#pragma unroll
    for (int off = 1; off < 64; off <<= 1) lmax = fmaxf(lmax, __shfl_xor(lmax, off));
    float lsum = 0.f;
    if (a0) {
#pragma unroll
        for (int j = 0; j < 8; ++j) { v[j] = __builtin_amdgcn_exp2f(v[j] - lmax); lsum += v[j]; }
    }
    if (a1) {
#pragma unroll
        for (int j = 0; j < 8; ++j) { v[8 + j] = __builtin_amdgcn_exp2f(v[8 + j] - lmax); lsum += v[8 + j]; }
    }
#pragma unroll
    for (int off = 1; off < 64; off <<= 1) lsum += __shfl_xor(lsum, off);
    const float inv = 1.f / lsum;
    if (a0) {
        bf16x8 c;
#pragma unroll
        for (int j = 0; j < 8; ++j) c[j] = (__bf16)(v[j] * inv);
        *(bf16x8*)(row + i0) = c;
    }
    if (a1) {
        bf16x8 c;
#pragma unroll
        for (int j = 0; j < 8; ++j) c[j] = (__bf16)(v[8 + j] * inv);
        *(bf16x8*)(row + i1) = c;
    }
}

// ---------------------------------------------------------------------------
// PV GEMM with chunked XCD swizzle: grid (32, 32) linear -> (z, mt, nt).
// ---------------------------------------------------------------------------
__global__ __launch_bounds__(256, 3) void gemm_pv(
    const __bf16* __restrict__ Sc, const __bf16* __restrict__ Vt,
    __bf16* __restrict__ ctx)
{
    int lin = blockIdx.x + 32 * blockIdx.y;          // 0..1023
    lin = (lin & 7) * 128 + (lin >> 3);              // bijective chunk swizzle
    const int z = lin >> 5;
    const int rem = lin & 31;
    const int mt = rem >> 2, nt = rem & 3;

    const int b = z >> 4, h = z & 15;
    const int Keff = (mt + 1) * 128;
    __shared__ __bf16 lds[768 * 32];
    const __bf16* Ab = Sc + (size_t)z * SS * SS;
    const __bf16* Bb = Vt + (size_t)b * 512 * 1024;
    const int tid = threadIdx.x;
    const int w = tid >> 6, lane = tid & 63, quad = lane >> 4, ln = lane & 15;
    const int m0 = mt * 128, n0 = nt * 128;
    const int wm = (w >> 1) * 64, wn = (w & 1) * 64;

    f32x4 acc[4][4];
#pragma unroll
    for (int i = 0; i < 4; ++i)
#pragma unroll
        for (int j = 0; j < 4; ++j) acc[i][j] = (f32x4){0.f, 0.f, 0.f, 0.f};

    gemm_core_tri<32>(Ab, Bb, SS, 1024, m0, n0, Keff, lds, acc);

#pragma unroll
    for (int mi = 0; mi < 4; ++mi)
#pragma unroll
        for (int r = 0; r < 4; ++r) {
            int row = m0 + wm + mi * 16 + quad * 4 + r;
            __bf16* op = ctx + (size_t)(b * SS + row) * (NHD * KVLR) + h * KVLR;
#pragma unroll
            for (int ni = 0; ni < 4; ++ni)
                op[n0 + wn + ni * 16 + ln] = (__bf16)acc[mi][ni][r];
        }
}

// ---------------------------------------------------------------------------
// Cast helpers
// ---------------------------------------------------------------------------
__global__ __launch_bounds__(256) void castf2b(const float* __restrict__ in,
                                               __bf16* __restrict__ out, int n)
{
    int i = (blockIdx.x * 256 + threadIdx.x) * 4;
    if (i < n) {
        float4 v = *(const float4*)(in + i);
        out[i] = (__bf16)v.x; out[i + 1] = (__bf16)v.y;
        out[i + 2] = (__bf16)v.z; out[i + 3] = (__bf16)v.w;
    }
}

// combined [w_qa(1536); w_kva(576); pad(64)] x 2048 -> bf16
__global__ __launch_bounds__(256) void cast_comb(const float* __restrict__ wqa,
                                                 const float* __restrict__ wkva,
                                                 __bf16* __restrict__ out)
{
    int idx = (blockIdx.x * 256 + threadIdx.x) * 4;
    int row = idx >> 11, col = idx & 2047;
    const float* src;
    if (row < 1536)      src = wqa + (size_t)row * 2048 + col;
    else if (row < 2112) src = wkva + (size_t)(row - 1536) * 2048 + col;
    else {
        out[idx] = (__bf16)0.f; out[idx + 1] = (__bf16)0.f;
        out[idx + 2] = (__bf16)0.f; out[idx + 3] = (__bf16)0.f;
        return;
    }
    float4 v = *(const float4*)src;
    out[idx] = (__bf16)v.x; out[idx + 1] = (__bf16)v.y;
    out[idx + 2] = (__bf16)v.z; out[idx + 3] = (__bf16)v.w;
}

// batched transpose-cast: in[z][R][C] fp32 -> out[z][C][R] bf16
__global__ __launch_bounds__(256) void transpose_cast(const float* __restrict__ in,
                                                      __bf16* __restrict__ out,
                                                      int R, int C)
{
    __shared__ float t[32][33];
    in  += (size_t)blockIdx.z * R * C;
    out += (size_t)blockIdx.z * R * C;
    int c0 = blockIdx.x * 32, r0 = blockIdx.y * 32;
    int tx = threadIdx.x & 31, ty = threadIdx.x >> 5;
#pragma unroll
    for (int i = 0; i < 4; ++i) {
        int r = ty + i * 8;
        t[r][tx] = in[(size_t)(r0 + r) * C + c0 + tx];
    }
    __syncthreads();
#pragma unroll
    for (int i = 0; i < 4; ++i) {
        int rr = ty + i * 8;
        out[(size_t)(c0 + rr) * R + r0 + tx] = (__bf16)t[tx][rr];
    }
}

// Kc[b][k][f<512] bf16 -> Vt[b][f][k] bf16 (key-contiguous V)
__global__ __launch_bounds__(256) void transpose_kc(const __bf16* __restrict__ Kc,
                                                    __bf16* __restrict__ Vt)
{
    __shared__ __bf16 t[32][33];
    int b = blockIdx.z;
    int k0 = blockIdx.x * 32, f0 = blockIdx.y * 32;
    int tx = threadIdx.x & 31, ty = threadIdx.x >> 5;   // ty 0..7
    const __bf16* src = Kc + (size_t)b * SS * 576;
#pragma unroll
    for (int i = 0; i < 4; ++i)
        t[ty + i * 8][tx] = src[(size_t)(k0 + ty + i * 8) * 576 + f0 + tx];
    __syncthreads();
    __bf16* dst = Vt + (size_t)b * 512 * 1024;
#pragma unroll
    for (int i = 0; i < 4; ++i)
        dst[(size_t)(f0 + ty + i * 8) * 1024 + k0 + tx] = t[tx][ty + i * 8];
}

// ---------------------------------------------------------------------------
// LayerNorm fp32 in (row stride ldx) -> bf16 out (row stride N).
// ---------------------------------------------------------------------------
__global__ __launch_bounds__(256) void ln_kernel(const float* __restrict__ x,
                                                 const float* __restrict__ w,
                                                 __bf16* __restrict__ y, int N, int ldx)
{
    long long row = blockIdx.x;
    const float* xr = x + row * ldx;
    __bf16* yr = y + row * N;
    int tid = threadIdx.x;
    float s = 0.f, ss = 0.f;
    for (int i = tid; i < N; i += 256) { float v = xr[i]; s += v; ss += v * v; }
#pragma unroll
    for (int off = 32; off > 0; off >>= 1) { s += __shfl_down(s, off); ss += __shfl_down(ss, off); }
    __shared__ float rs[4], rss[4];
    __shared__ float smean, sinv;
    int wave = tid >> 6, lane = tid & 63;
    if (lane == 0) { rs[wave] = s; rss[wave] = ss; }
    __syncthreads();
    if (tid == 0) {
        float S = rs[0] + rs[1] + rs[2] + rs[3];
        float Q = rss[0] + rss[1] + rss[2] + rss[3];
        float mean = S / N;
        float var = Q / N - mean * mean;
        smean = mean; sinv = rsqrtf(var + EPSF);
    }
    __syncthreads();
    float mean = smean, inv = sinv;
    for (int i = tid; i < N; i += 256) yr[i] = (__bf16)((xr[i] - mean) * inv * w[i]);
}

// ---------------------------------------------------------------------------
// Per-token prep: Kc[row] = bf16(concat(LN(kva[:512])*w, rope(kva[512:576])))
// kva row stride ld; roped q_pe written straight into Qc cols [512,576).
// ---------------------------------------------------------------------------
__global__ __launch_bounds__(256) void prep_kernel(
    const float* __restrict__ kva, int ld, const float* __restrict__ kvw,
    const float* __restrict__ cosb, const float* __restrict__ sinb,
    __bf16* __restrict__ Kc, const __bf16* __restrict__ q,
    __bf16* __restrict__ Qc)
{
    long long row = blockIdx.x;
    const float* kr = kva + row * ld;
    const float* cr = cosb + row * ROPED;
    const float* sr = sinb + row * ROPED;
    int tid = threadIdx.x;
    float v0 = kr[tid], v1 = kr[tid + 256];
    float s = v0 + v1, ss = v0 * v0 + v1 * v1;
#pragma unroll
    for (int off = 32; off > 0; off >>= 1) { s += __shfl_down(s, off); ss += __shfl_down(ss, off); }
    __shared__ float rs[4], rss[4];
    __shared__ float smean, sinv;
    int wave = tid >> 6, lane = tid & 63;
    if (lane == 0) { rs[wave] = s; rss[wave] = ss; }
    __syncthreads();
    if (tid == 0) {
        float S = rs[0] + rs[1] + rs[2] + rs[3];
        float Q = rss[0] + rss[1] + rss[2] + rss[3];
        float mean = S / KVLR;
        float var = Q / KVLR - mean * mean;
        smean = mean; sinv = rsqrtf(var + EPSF);
    }
    __syncthreads();
    float mean = smean, inv = sinv;
    __bf16* kc = Kc + row * 576;
    kc[tid]       = (__bf16)((v0 - mean) * inv * kvw[tid]);
    kc[tid + 256] = (__bf16)((v1 - mean) * inv * kvw[tid + 256]);
    if (tid < 32) {
        float x1 = kr[KVLR + tid], x2 = kr[KVLR + 32 + tid];
        kc[512 + tid]      = (__bf16)(x1 * cr[tid] - x2 * sr[tid]);
        kc[512 + 32 + tid] = (__bf16)(x2 * cr[32 + tid] + x1 * sr[32 + tid]);
    }
    const int bb = (int)(row >> 10), sp = (int)(row & 1023);
    const __bf16* qr = q + row * (NHD * QKD);
#pragma unroll
    for (int j = 0; j < 2; ++j) {
        int idx = tid + j * 256;
        int h = idx >> 5, p = idx & 31;
        const __bf16* base = qr + h * QKD + NOPE;
        float x1 = (float)base[p], x2 = (float)base[32 + p];
        __bf16* qcb = Qc + ((size_t)(bb * NHD + h) * SS + sp) * 576 + 512;
        qcb[p]      = (__bf16)(x1 * cr[p] - x2 * sr[p]);
        qcb[32 + p] = (__bf16)(x2 * cr[32 + p] + x1 * sr[32 + p]);
    }
}

// ---------------------------------------------------------------------------
extern "C" void kernel_launch(void* const* d_in, const int* in_sizes, int n_in,
                              void* d_out, int out_size, void* d_ws, size_t ws_size,
                              hipStream_t stream)
{
    const float* hidden    = (const float*)d_in[0];
    const float* cosb      = (const float*)d_in[1];
    const float* sinb      = (const float*)d_in[2];
    const float* w_qa      = (const float*)d_in[3];
    const float* q_a_ln_w  = (const float*)d_in[4];
    const float* w_qb      = (const float*)d_in[5];
    const float* w_kva     = (const float*)d_in[6];
    const float* kv_a_ln_w = (const float*)d_in[7];
    const float* W_UK_T    = (const float*)d_in[8];
    const float* W_UV      = (const float*)d_in[9];
    const float* w_o       = (const float*)d_in[10];
    float* out = (float*)d_out;

    const int M = BB * SS;  // 2048
    // ---- HEAD region: transient buffers, later aliased by Sc (67.1 MB) ----
    float*  qakva = (float*)d_ws;
    __bf16* Xb    = (__bf16*)(qakva + (size_t)M * NCOMB);
    __bf16* qab   = Xb    + (size_t)M * HH;
    __bf16* qb    = qab   + (size_t)M * QLR;
    __bf16* qlatb = qb    + (size_t)M * NHD * QKD;   // slot kept (unused now)
    __bf16* Sc    = (__bf16*)d_ws;                    // aliases head after qlat
    // ---- TAIL region: persistent ----
    __bf16* Kc    = qlatb + (size_t)M * NHD * KVLR;   // M*576
    __bf16* Qc    = Kc    + (size_t)M * 576;          // M*9216
    __bf16* Vt    = Qc    + (size_t)M * NHD * 576;    // 2*512*1024
    __bf16* ctxb  = Vt    + (size_t)BB * 512 * SS;    // M*8192
    __bf16* ohb   = ctxb  + (size_t)M * NHD * KVLR;   // M*2048
    __bf16* w_cmb = ohb   + (size_t)M * HH;           // 2176*2048
    __bf16* w_qbb = w_cmb + (size_t)NCOMB * HH;       // 3072*1536
    __bf16* Wkb   = w_qbb + (size_t)NHD * QKD * QLR;  // 16*512*128
    __bf16* Wvb   = Wkb   + (size_t)NHD * KVLR * NOPE;// 16*128*512
    __bf16* w_ob  = Wvb   + (size_t)NHD * VDIM * KVLR;// 2048*2048

    dim3 blk(256);

    // --- casts ---
    castf2b<<<dim3((M * HH) / 1024), blk, 0, stream>>>(hidden, Xb, M * HH);
    cast_comb<<<dim3((NCOMB * HH) / 1024), blk, 0, stream>>>(w_qa, w_kva, w_cmb);
    castf2b<<<dim3((NHD * QKD * QLR) / 1024), blk, 0, stream>>>(w_qb, w_qbb, NHD * QKD * QLR);
    castf2b<<<dim3((HH * HH) / 1024), blk, 0, stream>>>(w_o, w_ob, HH * HH);
    transpose_cast<<<dim3(KVLR / 32, NOPE / 32, NHD), blk, 0, stream>>>(W_UK_T, Wkb, NOPE, KVLR);
    transpose_cast<<<dim3(VDIM / 32, KVLR / 32, NHD), blk, 0, stream>>>(W_UV, Wvb, KVLR, VDIM);

    // 1+4 fused: qakva = Xb @ [w_qa; w_kva]^T   (2048 x 2176 x 2048)
    gemm_mfma<false, 64, 2, false><<<dim3(NCOMB / 128, M / 128, 1), blk, 0, stream>>>(
        Xb, w_cmb, qakva, M, NCOMB, HH, HH, HH, NCOMB, 0, 0, 0);
    // 2. qab = bf16(LN(qakva[:, :1536]))
    ln_kernel<<<dim3(M), blk, 0, stream>>>(qakva, q_a_ln_w, qab, QLR, NCOMB);
    // 3. qb = qab @ w_qb^T (bf16)              (2048 x 3072 x 1536)
    gemm_mfma<true, 64, 2, false><<<dim3(NHD * QKD / 128, M / 128, 1), blk, 0, stream>>>(
        qab, w_qbb, qb, M, NHD * QKD, QLR, QLR, QLR, NHD * QKD, 0, 0, 0);
    // 5. Kc = [LN(kv_c), rope(k_pe)] bf16; roped q_pe -> Qc[...,512:576)
    prep_kernel<<<dim3(M), blk, 0, stream>>>(qakva + QLR, NCOMB, kv_a_ln_w,
                                             cosb, sinb, Kc, qb, Qc);
    // 5b. Vt = transpose(Kc[:, :512])
    transpose_kc<<<dim3(SS / 32, 512 / 32, BB), blk, 0, stream>>>(Kc, Vt);
    // 6. Qc[...,0:512) = q_nope[h] @ Wkb[h]^T  (16 x [2048 x 512 x 128])
    gemm_qlat<<<dim3(KVLR / 128, M / 128, NHD), blk, 0, stream>>>(qb, Wkb, Qc);
    // 8a. Sc = causal scores, exact triangle grid (1152 blocks)
    gemm_scores<<<dim3(36, 32), blk, 0, stream>>>(Qc, Kc, Sc);
    // 8b. row softmax in place
    softmax_kernel<<<dim3(SS / 4, 32), blk, 0, stream>>>(Sc);
    // 8c. ctx = P @ V (causal k-bound), linear grid + swizzle
    gemm_pv<<<dim3(32, 32), blk, 0, stream>>>(Sc, Vt, ctxb);
    // 9. ohb[h] = ctx[h] @ Wvb[h]^T            (16 x [2048 x 128 x 512])
    gemm_mfma<true, 32, 3, true><<<dim3(VDIM / 128, M / 128, NHD), blk, 0, stream>>>(
        ctxb, Wvb, ohb, M, VDIM, KVLR,
        NHD * KVLR, KVLR, NHD * VDIM,
        (long long)KVLR, (long long)VDIM * KVLR, (long long)VDIM);
    // 10. out = ohb @ w_o^T (fp32)             (2048 x 2048 x 2048)
    gemm_mfma<false, 64, 2, false><<<dim3(HH / 128, M / 128, 1), blk, 0, stream>>>(
        ohb, w_ob, out, M, HH, NHD * VDIM, NHD * VDIM, NHD * VDIM, HH, 0, 0, 0);
}

// Round 7
// 311.350 us; speedup vs baseline: 1.1585x; 1.0661x over previous
//
#include <hip/hip_runtime.h>
#include <hip/hip_bf16.h>
#include <math.h>

#define BB 2
#define SS 1024
#define HH 2048
#define NHD 16
#define NOPE 128
#define ROPED 64
#define VDIM 128
#define QKD 192
#define QLR 1536
#define KVLR 512
#define EPSF 1e-5f
#define NCOMB 2176   // QLR + 576 kv + 64 pad

typedef __bf16 bf16x8 __attribute__((ext_vector_type(8)));
typedef float  f32x4  __attribute__((ext_vector_type(4)));

__device__ __forceinline__ void gload_lds16(const __bf16* g, __bf16* l) {
    __builtin_amdgcn_global_load_lds(
        (const __attribute__((address_space(1))) void*)g,
        (__attribute__((address_space(3))) void*)l, 16, 0, 0);
}

// XCD-chunked bijective tile swizzle (T1, validated R6: FETCH drop + ~8 µs).
__device__ __forceinline__ void swz2d(int nx, int ny, int& bx, int& by) {
    int T = nx * ny;
    int lin = blockIdx.x + nx * blockIdx.y;
    if ((T & 7) == 0) {
        int q = T >> 3;
        lin = (lin & 7) * q + (lin >> 3);
    }
    bx = lin % nx;
    by = lin / nx;
}

// ---------------------------------------------------------------------------
// Double-buffered 2-barrier core (R1 schedule, proven): for dense big-K GEMMs.
// XOR swizzle (both-sides involution, verified): BK=64 chunk^=row&7.
// ---------------------------------------------------------------------------
template<int BK>
__device__ __forceinline__ void gemm_core_dbuf(
    const __bf16* __restrict__ Ab, const __bf16* __restrict__ Bb,
    int lda, int ldb, int m0, int n0, int K, __bf16* lds, f32x4 acc[4][4])
{
    constexpr int CH    = BK / 8;
    constexpr int LPT   = CH / 2;
    constexpr int BUFE  = 256 * BK;
    constexpr int BOFF  = 128 * BK;
    constexpr int RSTEP = 2048 / BK;
    const int tid = threadIdx.x;
    const int w = tid >> 6, lane = tid & 63, quad = lane >> 4, ln = lane & 15;
    const int wm = (w >> 1) * 64, wn = (w & 1) * 64;
    const int nt = K / BK;

    const int sr  = tid / CH;
    const int spc = tid % CH;
    const int sc  = (BK == 64) ? (spc ^ (sr & 7)) : (spc ^ ((sr >> 1) & 3));
    const __bf16* gA = Ab + (size_t)(m0 + sr) * lda + sc * 8;
    const __bf16* gB = Bb + (size_t)(n0 + sr) * ldb + sc * 8;

    const int swm = (BK == 64) ? ((wm + ln) & 7) : (((wm + ln) >> 1) & 3);
    const int swn = (BK == 64) ? ((wn + ln) & 7) : (((wn + ln) >> 1) & 3);

    auto stage = [&](int buf, int kk) {
        __bf16* la = lds + buf * BUFE + w * 512;
        __bf16* lb = la + BOFF;
        const __bf16* ga = gA + kk;
        const __bf16* gb = gB + kk;
#pragma unroll
        for (int i = 0; i < LPT; ++i) {
            gload_lds16(ga + (size_t)(i * RSTEP) * lda, la + i * 2048);
            gload_lds16(gb + (size_t)(i * RSTEP) * ldb, lb + i * 2048);
        }
    };
    auto wait_stage = [&]() {
        if constexpr (BK == 64) asm volatile("s_waitcnt vmcnt(8)" ::: "memory");
        else                    asm volatile("s_waitcnt vmcnt(4)" ::: "memory");
    };

    stage(0, 0);
    stage(1, BK);
    wait_stage();
    __builtin_amdgcn_s_barrier();
    __builtin_amdgcn_sched_barrier(0);

    for (int t = 0; t < nt; ++t) {
        const int cur = t & 1;
        const __bf16* bufA = lds + cur * BUFE;
        const __bf16* bufB = bufA + BOFF;
        bf16x8 af[BK / 32][4], bv[BK / 32][4];
#pragma unroll
        for (int ks = 0; ks < BK / 32; ++ks)
#pragma unroll
            for (int i = 0; i < 4; ++i) {
                af[ks][i] = *(const bf16x8*)
                    &bufA[(wm + ln) * BK + i * 16 * BK + (((ks * 4 + quad) ^ swm) << 3)];
                bv[ks][i] = *(const bf16x8*)
                    &bufB[(wn + ln) * BK + i * 16 * BK + (((ks * 4 + quad) ^ swn) << 3)];
            }
        __builtin_amdgcn_s_setprio(1);
#pragma unroll
        for (int ks = 0; ks < BK / 32; ++ks)
#pragma unroll
            for (int mi = 0; mi < 4; ++mi)
#pragma unroll
                for (int ni = 0; ni < 4; ++ni)
                    acc[mi][ni] = __builtin_amdgcn_mfma_f32_16x16x32_bf16(
                        af[ks][mi], bv[ks][ni], acc[mi][ni], 0, 0, 0);
        __builtin_amdgcn_s_setprio(0);
        if (t + 1 < nt) {
            __builtin_amdgcn_sched_barrier(0);
            asm volatile("" ::: "memory");
            __builtin_amdgcn_s_barrier();          // (a) reads of buf[cur] done
            asm volatile("" ::: "memory");
            if (t + 2 < nt) {
                stage(cur, (t + 2) * BK);
                wait_stage();
            } else {
                asm volatile("s_waitcnt vmcnt(0)" ::: "memory");
            }
            __builtin_amdgcn_s_barrier();          // (b) publish t+1
            __builtin_amdgcn_sched_barrier(0);
        }
    }
}

// ---------------------------------------------------------------------------
// Triple-buffered 1-barrier core (BK=32: 48 KB LDS -> 3 blocks/CU).
// Race screen in R3/R4 notes; proven since R4.
// ---------------------------------------------------------------------------
template<int BK>
__device__ __forceinline__ void gemm_core_tri(
    const __bf16* __restrict__ Ab, const __bf16* __restrict__ Bb,
    int lda, int ldb, int m0, int n0, int K, __bf16* lds, f32x4 acc[4][4])
{
    constexpr int CH    = BK / 8;
    constexpr int LPT   = CH / 2;
    constexpr int BUFE  = 256 * BK;
    constexpr int BOFF  = 128 * BK;
    constexpr int RSTEP = 2048 / BK;
    const int tid = threadIdx.x;
    const int w = tid >> 6, lane = tid & 63, quad = lane >> 4, ln = lane & 15;
    const int wm = (w >> 1) * 64, wn = (w & 1) * 64;
    const int nt = K / BK;

    const int sr  = tid / CH;
    const int spc = tid % CH;
    const int sc  = (BK == 64) ? (spc ^ (sr & 7)) : (spc ^ ((sr >> 1) & 3));
    const __bf16* gA = Ab + (size_t)(m0 + sr) * lda + sc * 8;
    const __bf16* gB = Bb + (size_t)(n0 + sr) * ldb + sc * 8;

    const int swm = (BK == 64) ? ((wm + ln) & 7) : (((wm + ln) >> 1) & 3);
    const int swn = (BK == 64) ? ((wn + ln) & 7) : (((wn + ln) >> 1) & 3);

    auto stage = [&](__bf16* base, int kk) {
        __bf16* la = base + w * 512;
        __bf16* lb = la + BOFF;
        const __bf16* ga = gA + kk;
        const __bf16* gb = gB + kk;
#pragma unroll
        for (int i = 0; i < LPT; ++i) {
            gload_lds16(ga + (size_t)(i * RSTEP) * lda, la + i * 2048);
            gload_lds16(gb + (size_t)(i * RSTEP) * ldb, lb + i * 2048);
        }
    };

    __bf16* p0 = lds;               // tile t
    __bf16* p1 = lds + BUFE;        // tile t+1
    __bf16* p2 = lds + 2 * BUFE;    // stage target (tile t+2)

    stage(p0, 0);
    stage(p1, BK);
    if constexpr (BK == 64) asm volatile("s_waitcnt vmcnt(8)" ::: "memory");
    else                    asm volatile("s_waitcnt vmcnt(4)" ::: "memory");
    __builtin_amdgcn_s_barrier();
    __builtin_amdgcn_sched_barrier(0);

    for (int t = 0; t < nt; ++t) {
        bf16x8 af[BK / 32][4], bv[BK / 32][4];
#pragma unroll
        for (int ks = 0; ks < BK / 32; ++ks)
#pragma unroll
            for (int i = 0; i < 4; ++i) {
                af[ks][i] = *(const bf16x8*)
                    &p0[(wm + ln) * BK + i * 16 * BK + (((ks * 4 + quad) ^ swm) << 3)];
                bv[ks][i] = *(const bf16x8*)
                    &p0[BOFF + (wn + ln) * BK + i * 16 * BK + (((ks * 4 + quad) ^ swn) << 3)];
            }
        if (t + 2 < nt) stage(p2, (t + 2) * BK);   // overwrites tile t-1's buf
        asm volatile("s_waitcnt lgkmcnt(0)" ::: "memory");
        __builtin_amdgcn_sched_barrier(0);
        __builtin_amdgcn_s_setprio(1);
#pragma unroll
        for (int ks = 0; ks < BK / 32; ++ks)
#pragma unroll
            for (int mi = 0; mi < 4; ++mi)
#pragma unroll
                for (int ni = 0; ni < 4; ++ni)
                    acc[mi][ni] = __builtin_amdgcn_mfma_f32_16x16x32_bf16(
                        af[ks][mi], bv[ks][ni], acc[mi][ni], 0, 0, 0);
        __builtin_amdgcn_s_setprio(0);
        if (t + 1 < nt) {
            __builtin_amdgcn_sched_barrier(0);
            if (t + 2 < nt) {
                if constexpr (BK == 64) asm volatile("s_waitcnt vmcnt(8)" ::: "memory");
                else                    asm volatile("s_waitcnt vmcnt(4)" ::: "memory");
            } else {
                asm volatile("s_waitcnt vmcnt(0)" ::: "memory");
            }
            __builtin_amdgcn_s_barrier();          // single barrier per tile
            __builtin_amdgcn_sched_barrier(0);
        }
        __bf16* tmp = p0; p0 = p1; p1 = p2; p2 = tmp;
    }
}

// ---------------------------------------------------------------------------
// MFMA bf16 GEMM: C[M,N] = A[M,K] @ B[N,K]^T (batched via blockIdx.z),
// with XCD-chunked tile swizzle.
// ---------------------------------------------------------------------------
template<bool OUT_BF16, int BK, int MINW, bool TRI>
__global__ __launch_bounds__(256, MINW) void gemm_mfma(
    const __bf16* __restrict__ A, const __bf16* __restrict__ B, void* __restrict__ Cv,
    int M, int N, int K, int lda, int ldb, int ldc,
    long long sA, long long sB, long long sC)
{
    __shared__ __bf16 lds[TRI ? 768 * BK : 512 * BK];
    const __bf16* Ab = A + (long long)blockIdx.z * sA;
    const __bf16* Bb = B + (long long)blockIdx.z * sB;
    const int tid = threadIdx.x;
    const int w = tid >> 6, lane = tid & 63, quad = lane >> 4, ln = lane & 15;
    int bx, by; swz2d(gridDim.x, gridDim.y, bx, by);
    const int m0 = by * 128, n0 = bx * 128;
    const int wm = (w >> 1) * 64, wn = (w & 1) * 64;

    f32x4 acc[4][4];
#pragma unroll
    for (int i = 0; i < 4; ++i)
#pragma unroll
        for (int j = 0; j < 4; ++j) acc[i][j] = (f32x4){0.f, 0.f, 0.f, 0.f};

    if (TRI) gemm_core_tri<BK>(Ab, Bb, lda, ldb, m0, n0, K, lds, acc);
    else     gemm_core_dbuf<BK>(Ab, Bb, lda, ldb, m0, n0, K, lds, acc);

    if (OUT_BF16) {
        __bf16* Cb = (__bf16*)Cv + (long long)blockIdx.z * sC;
#pragma unroll
        for (int mi = 0; mi < 4; ++mi)
#pragma unroll
            for (int r = 0; r < 4; ++r) {
                size_t row = (size_t)(m0 + wm + mi * 16 + quad * 4 + r);
#pragma unroll
                for (int ni = 0; ni < 4; ++ni)
                    Cb[row * ldc + (n0 + wn + ni * 16 + ln)] = (__bf16)acc[mi][ni][r];
            }
    } else {
        float* Cb = (float*)Cv + (long long)blockIdx.z * sC;
#pragma unroll
        for (int mi = 0; mi < 4; ++mi)
#pragma unroll
            for (int r = 0; r < 4; ++r) {
                size_t row = (size_t)(m0 + wm + mi * 16 + quad * 4 + r);
#pragma unroll
                for (int ni = 0; ni < 4; ++ni)
                    Cb[row * ldc + (n0 + wn + ni * 16 + ln)] = acc[mi][ni][r];
            }
    }
}

// ---------------------------------------------------------------------------
// qlat GEMM with fused Qc scatter: Qc[b][h][s][0..512) = q_nope[h] @ Wk[h]^T
// ---------------------------------------------------------------------------
__global__ __launch_bounds__(256, 3) void gemm_qlat(
    const __bf16* __restrict__ qb, const __bf16* __restrict__ Wkb,
    __bf16* __restrict__ Qc)
{
    __shared__ __bf16 lds[768 * 32];
    const int h = blockIdx.z;
    const __bf16* Ab = qb + (size_t)h * QKD;
    const __bf16* Bb = Wkb + (size_t)h * KVLR * NOPE;
    const int tid = threadIdx.x;
    const int w = tid >> 6, lane = tid & 63, quad = lane >> 4, ln = lane & 15;
    int bx, by; swz2d(gridDim.x, gridDim.y, bx, by);
    const int m0 = by * 128, n0 = bx * 128;
    const int wm = (w >> 1) * 64, wn = (w & 1) * 64;

    f32x4 acc[4][4];
#pragma unroll
    for (int i = 0; i < 4; ++i)
#pragma unroll
        for (int j = 0; j < 4; ++j) acc[i][j] = (f32x4){0.f, 0.f, 0.f, 0.f};

    gemm_core_tri<32>(Ab, Bb, NHD * QKD, NOPE, m0, n0, NOPE, lds, acc);

#pragma unroll
    for (int mi = 0; mi < 4; ++mi)
#pragma unroll
        for (int r = 0; r < 4; ++r) {
            int row = m0 + wm + mi * 16 + quad * 4 + r;   // b*S + s
            int bb = row >> 10, s = row & 1023;
            __bf16* dst = Qc + ((size_t)(bb * NHD + h) * SS + s) * 576;
#pragma unroll
            for (int ni = 0; ni < 4; ++ni)
                dst[n0 + wn + ni * 16 + ln] = (__bf16)acc[mi][ni][r];
        }
}

// ---------------------------------------------------------------------------
// Vh GEMM (new, R7): Vh[z=b*16+h][128v][1024s] = Wvb[h] @ Kc[b][:, :512]^T.
// A = Wvb[h] [128][512] (lda 512), B = Kc[b] rows [1024][512] (ldb 576).
// Output is directly the B-operand layout PV needs. Grid (8, 1, 32), XCD
// chunk swizzle over (n-tile, z) so each XCD reuses one Kc[b] from its L2.
// ---------------------------------------------------------------------------
__global__ __launch_bounds__(256, 3) void gemm_vh(
    const __bf16* __restrict__ Wvb, const __bf16* __restrict__ Kc,
    __bf16* __restrict__ Vh)
{
    int lin = blockIdx.x + 8 * blockIdx.z;           // 0..255
    lin = (lin & 7) * 32 + (lin >> 3);               // bijective chunk swizzle
    const int z = lin >> 3;
    const int ntile = lin & 7;
    const int b = z >> 4, h = z & 15;

    __shared__ __bf16 lds[768 * 32];
    const __bf16* Ab = Wvb + (size_t)h * VDIM * KVLR;
    const __bf16* Bb = Kc + (size_t)b * SS * 576;
    const int tid = threadIdx.x;
    const int w = tid >> 6, lane = tid & 63, quad = lane >> 4, ln = lane & 15;
    const int m0 = 0, n0 = ntile * 128;
    const int wm = (w >> 1) * 64, wn = (w & 1) * 64;

    f32x4 acc[4][4];
#pragma unroll
    for (int i = 0; i < 4; ++i)
#pragma unroll
        for (int j = 0; j < 4; ++j) acc[i][j] = (f32x4){0.f, 0.f, 0.f, 0.f};

    gemm_core_tri<32>(Ab, Bb, KVLR, 576, m0, n0, KVLR, lds, acc);

    __bf16* Cb = Vh + (size_t)z * VDIM * SS;         // [128][1024]
#pragma unroll
    for (int mi = 0; mi < 4; ++mi)
#pragma unroll
        for (int r = 0; r < 4; ++r) {
            int row = m0 + wm + mi * 16 + quad * 4 + r;
#pragma unroll
            for (int ni = 0; ni < 4; ++ni)
                Cb[(size_t)row * SS + (n0 + wn + ni * 16 + ln)] = (__bf16)acc[mi][ni][r];
        }
}

// ---------------------------------------------------------------------------
// Causal scores GEMM, exact-triangle grid + chunked XCD swizzle.
// ---------------------------------------------------------------------------
__global__ __launch_bounds__(256, 3) void gemm_scores(
    const __bf16* __restrict__ Qc, const __bf16* __restrict__ Kc,
    __bf16* __restrict__ Sc)
{
    int lin = blockIdx.x + 36 * blockIdx.y;          // 0..1151
    lin = (lin & 7) * 144 + (lin >> 3);              // bijective chunk swizzle
    const int z = lin / 36;
    const int i = lin - z * 36;
    int mt = (int)((sqrtf(8.f * i + 1.f) - 1.f) * 0.5f);
    if (mt * (mt + 1) / 2 > i) --mt;
    if ((mt + 1) * (mt + 2) / 2 <= i) ++mt;
    const int nt = i - mt * (mt + 1) / 2;

    const int b = z >> 4;
    __shared__ __bf16 lds[768 * 32];
    const __bf16* Ab = Qc + (size_t)z * SS * 576;
    const __bf16* Bb = Kc + (size_t)b * SS * 576;
    __bf16* Cb = Sc + (size_t)z * SS * SS;
    const int tid = threadIdx.x;
    const int w = tid >> 6, lane = tid & 63, quad = lane >> 4, ln = lane & 15;
    const int m0 = mt * 128, n0 = nt * 128;
    const int wm = (w >> 1) * 64, wn = (w & 1) * 64;

    f32x4 acc[4][4];
#pragma unroll
    for (int i2 = 0; i2 < 4; ++i2)
#pragma unroll
        for (int j = 0; j < 4; ++j) acc[i2][j] = (f32x4){0.f, 0.f, 0.f, 0.f};

    gemm_core_tri<32>(Ab, Bb, 576, 576, m0, n0, 576, lds, acc);

    const float SCL2 = 0.07216878364870323f * 1.4426950408889634f;  // scale*log2e
#pragma unroll
    for (int mi = 0; mi < 4; ++mi)
#pragma unroll
        for (int r = 0; r < 4; ++r) {
            int row = m0 + wm + mi * 16 + quad * 4 + r;
#pragma unroll
            for (int ni = 0; ni < 4; ++ni) {
                int col = n0 + wn + ni * 16 + ln;
                float v = acc[mi][ni][r] * SCL2;
                if (col > row) v = -1e30f;
                Cb[(size_t)row * SS + col] = (__bf16)v;
            }
        }
}

// ---------------------------------------------------------------------------
// Row softmax (exp2 domain). One wave per row, shfl-only reductions.
// ---------------------------------------------------------------------------
__global__ __launch_bounds__(256) void softmax_kernel(__bf16* __restrict__ Sc)
{
    const int z = blockIdx.y;
    const int w = threadIdx.x >> 6, lane = threadIdx.x & 63;
    const int r = blockIdx.x * 4 + w;
    __bf16* row = Sc + (size_t)z * SS * SS + (size_t)r * SS;
    const int ncols = ((r >> 7) + 1) << 7;
    const int i0 = lane * 8, i1 = i0 + 512;
    const bool a0 = i0 < ncols, a1 = i1 < ncols;
    float v[16];
    float lmax = -1e30f;
    if (a0) {
        bf16x8 c = *(const bf16x8*)(row + i0);
#pragma unroll
        for (int j = 0; j < 8; ++j) { v[j] = (float)c[j]; lmax = fmaxf(lmax, v[j]); }
    }
    if (a1) {
        bf16x8 c = *(const bf16x8*)(row + i1);
#pragma unroll
        for (int j = 0; j < 8; ++j) { v[8 + j] = (float)c[j]; lmax = fmaxf(lmax, v[8 + j]); }
    }
#pragma unroll
    for (int off = 1; off < 64; off <<= 1) lmax = fmaxf(lmax, __shfl_xor(lmax, off));
    float lsum = 0.f;
    if (a0) {
#pragma unroll
        for (int j = 0; j < 8; ++j) { v[j] = __builtin_amdgcn_exp2f(v[j] - lmax); lsum += v[j]; }
    }
    if (a1) {
#pragma unroll
        for (int j = 0; j < 8; ++j) { v[8 + j] = __builtin_amdgcn_exp2f(v[8 + j] - lmax); lsum += v[8 + j]; }
    }
#pragma unroll
    for (int off = 1; off < 64; off <<= 1) lsum += __shfl_xor(lsum, off);
    const float inv = 1.f / lsum;
    if (a0) {
        bf16x8 c;
#pragma unroll
        for (int j = 0; j < 8; ++j) c[j] = (__bf16)(v[j] * inv);
        *(bf16x8*)(row + i0) = c;
    }
    if (a1) {
        bf16x8 c;
#pragma unroll
        for (int j = 0; j < 8; ++j) c[j] = (__bf16)(v[8 + j] * inv);
        *(bf16x8*)(row + i1) = c;
    }
}

// ---------------------------------------------------------------------------
// PV GEMM (R7, head-space): ohb[b, s, h*128+v] = P[z] @ Vh[z]^T.
// B operand = Vh[z] [128v][1024s] (ldb SS). N=128 -> single n-tile.
// Causal k-bound: K_eff = (mt+1)*128. Grid (8, 32) -> (mt, z) via chunk
// swizzle (each XCD gets 4 consecutive z's; Sc[z]+Vh[z] L2-resident).
// ---------------------------------------------------------------------------
__global__ __launch_bounds__(256, 3) void gemm_pv(
    const __bf16* __restrict__ Sc, const __bf16* __restrict__ Vh,
    __bf16* __restrict__ ohb)
{
    int lin = blockIdx.x + 8 * blockIdx.y;           // 0..255
    lin = (lin & 7) * 32 + (lin >> 3);               // bijective chunk swizzle
    const int z = lin >> 3;
    const int mt = lin & 7;

    const int b = z >> 4, h = z & 15;
    const int Keff = (mt + 1) * 128;
    __shared__ __bf16 lds[768 * 32];
    const __bf16* Ab = Sc + (size_t)z * SS * SS;
    const __bf16* Bb = Vh + (size_t)z * VDIM * SS;
    const int tid = threadIdx.x;
    const int w = tid >> 6, lane = tid & 63, quad = lane >> 4, ln = lane & 15;
    const int m0 = mt * 128, n0 = 0;
    const int wm = (w >> 1) * 64, wn = (w & 1) * 64;

    f32x4 acc[4][4];
#pragma unroll
    for (int i = 0; i < 4; ++i)
#pragma unroll
        for (int j = 0; j < 4; ++j) acc[i][j] = (f32x4){0.f, 0.f, 0.f, 0.f};

    gemm_core_tri<32>(Ab, Bb, SS, SS, m0, n0, Keff, lds, acc);

#pragma unroll
    for (int mi = 0; mi < 4; ++mi)
#pragma unroll
        for (int r = 0; r < 4; ++r) {
            int row = m0 + wm + mi * 16 + quad * 4 + r;
            __bf16* op = ohb + (size_t)(b * SS + row) * (NHD * VDIM) + h * VDIM;
#pragma unroll
            for (int ni = 0; ni < 4; ++ni)
                op[n0 + wn + ni * 16 + ln] = (__bf16)acc[mi][ni][r];
        }
}

// ---------------------------------------------------------------------------
// Cast helpers
// ---------------------------------------------------------------------------
__global__ __launch_bounds__(256) void castf2b(const float* __restrict__ in,
                                               __bf16* __restrict__ out, int n)
{
    int i = (blockIdx.x * 256 + threadIdx.x) * 4;
    if (i < n) {
        float4 v = *(const float4*)(in + i);
        out[i] = (__bf16)v.x; out[i + 1] = (__bf16)v.y;
        out[i + 2] = (__bf16)v.z; out[i + 3] = (__bf16)v.w;
    }
}

// combined [w_qa(1536); w_kva(576); pad(64)] x 2048 -> bf16
__global__ __launch_bounds__(256) void cast_comb(const float* __restrict__ wqa,
                                                 const float* __restrict__ wkva,
                                                 __bf16* __restrict__ out)
{
    int idx = (blockIdx.x * 256 + threadIdx.x) * 4;
    int row = idx >> 11, col = idx & 2047;
    const float* src;
    if (row < 1536)      src = wqa + (size_t)row * 2048 + col;
    else if (row < 2112) src = wkva + (size_t)(row - 1536) * 2048 + col;
    else {
        out[idx] = (__bf16)0.f; out[idx + 1] = (__bf16)0.f;
        out[idx + 2] = (__bf16)0.f; out[idx + 3] = (__bf16)0.f;
        return;
    }
    float4 v = *(const float4*)src;
    out[idx] = (__bf16)v.x; out[idx + 1] = (__bf16)v.y;
    out[idx + 2] = (__bf16)v.z; out[idx + 3] = (__bf16)v.w;
}

// batched transpose-cast: in[z][R][C] fp32 -> out[z][C][R] bf16
__global__ __launch_bounds__(256) void transpose_cast(const float* __restrict__ in,
                                                      __bf16* __restrict__ out,
                                                      int R, int C)
{
    __shared__ float t[32][33];
    in  += (size_t)blockIdx.z * R * C;
    out += (size_t)blockIdx.z * R * C;
    int c0 = blockIdx.x * 32, r0 = blockIdx.y * 32;
    int tx = threadIdx.x & 31, ty = threadIdx.x >> 5;
#pragma unroll
    for (int i = 0; i < 4; ++i) {
        int r = ty + i * 8;
        t[r][tx] = in[(size_t)(r0 + r) * C + c0 + tx];
    }
    __syncthreads();
#pragma unroll
    for (int i = 0; i < 4; ++i) {
        int rr = ty + i * 8;
        out[(size_t)(c0 + rr) * R + r0 + tx] = (__bf16)t[tx][rr];
    }
}

// ---------------------------------------------------------------------------
// LayerNorm fp32 in (row stride ldx) -> bf16 out (row stride N).
// ---------------------------------------------------------------------------
__global__ __launch_bounds__(256) void ln_kernel(const float* __restrict__ x,
                                                 const float* __restrict__ w,
                                                 __bf16* __restrict__ y, int N, int ldx)
{
    long long row = blockIdx.x;
    const float* xr = x + row * ldx;
    __bf16* yr = y + row * N;
    int tid = threadIdx.x;
    float s = 0.f, ss = 0.f;
    for (int i = tid; i < N; i += 256) { float v = xr[i]; s += v; ss += v * v; }
#pragma unroll
    for (int off = 32; off > 0; off >>= 1) { s += __shfl_down(s, off); ss += __shfl_down(ss, off); }
    __shared__ float rs[4], rss[4];
    __shared__ float smean, sinv;
    int wave = tid >> 6, lane = tid & 63;
    if (lane == 0) { rs[wave] = s; rss[wave] = ss; }
    __syncthreads();
    if (tid == 0) {
        float S = rs[0] + rs[1] + rs[2] + rs[3];
        float Q = rss[0] + rss[1] + rss[2] + rss[3];
        float mean = S / N;
        float var = Q / N - mean * mean;
        smean = mean; sinv = rsqrtf(var + EPSF);
    }
    __syncthreads();
    float mean = smean, inv = sinv;
    for (int i = tid; i < N; i += 256) yr[i] = (__bf16)((xr[i] - mean) * inv * w[i]);
}

// ---------------------------------------------------------------------------
// Per-token prep: Kc[row] = bf16(concat(LN(kva[:512])*w, rope(kva[512:576])))
// kva row stride ld; roped q_pe written straight into Qc cols [512,576).
// ---------------------------------------------------------------------------
__global__ __launch_bounds__(256) void prep_kernel(
    const float* __restrict__ kva, int ld, const float* __restrict__ kvw,
    const float* __restrict__ cosb, const float* __restrict__ sinb,
    __bf16* __restrict__ Kc, const __bf16* __restrict__ q,
    __bf16* __restrict__ Qc)
{
    long long row = blockIdx.x;
    const float* kr = kva + row * ld;
    const float* cr = cosb + row * ROPED;
    const float* sr = sinb + row * ROPED;
    int tid = threadIdx.x;
    float v0 = kr[tid], v1 = kr[tid + 256];
    float s = v0 + v1, ss = v0 * v0 + v1 * v1;
#pragma unroll
    for (int off = 32; off > 0; off >>= 1) { s += __shfl_down(s, off); ss += __shfl_down(ss, off); }
    __shared__ float rs[4], rss[4];
    __shared__ float smean, sinv;
    int wave = tid >> 6, lane = tid & 63;
    if (lane == 0) { rs[wave] = s; rss[wave] = ss; }
    __syncthreads();
    if (tid == 0) {
        float S = rs[0] + rs[1] + rs[2] + rs[3];
        float Q = rss[0] + rss[1] + rss[2] + rss[3];
        float mean = S / KVLR;
        float var = Q / KVLR - mean * mean;
        smean = mean; sinv = rsqrtf(var + EPSF);
    }
    __syncthreads();
    float mean = smean, inv = sinv;
    __bf16* kc = Kc + row * 576;
    kc[tid]       = (__bf16)((v0 - mean) * inv * kvw[tid]);
    kc[tid + 256] = (__bf16)((v1 - mean) * inv * kvw[tid + 256]);
    if (tid < 32) {
        float x1 = kr[KVLR + tid], x2 = kr[KVLR + 32 + tid];
        kc[512 + tid]      = (__bf16)(x1 * cr[tid] - x2 * sr[tid]);
        kc[512 + 32 + tid] = (__bf16)(x2 * cr[32 + tid] + x1 * sr[32 + tid]);
    }
    const int bb = (int)(row >> 10), sp = (int)(row & 1023);
    const __bf16* qr = q + row * (NHD * QKD);
#pragma unroll
    for (int j = 0; j < 2; ++j) {
        int idx = tid + j * 256;
        int h = idx >> 5, p = idx & 31;
        const __bf16* base = qr + h * QKD + NOPE;
        float x1 = (float)base[p], x2 = (float)base[32 + p];
        __bf16* qcb = Qc + ((size_t)(bb * NHD + h) * SS + sp) * 576 + 512;
        qcb[p]      = (__bf16)(x1 * cr[p] - x2 * sr[p]);
        qcb[32 + p] = (__bf16)(x2 * cr[32 + p] + x1 * sr[32 + p]);
    }
}

// ---------------------------------------------------------------------------
extern "C" void kernel_launch(void* const* d_in, const int* in_sizes, int n_in,
                              void* d_out, int out_size, void* d_ws, size_t ws_size,
                              hipStream_t stream)
{
    const float* hidden    = (const float*)d_in[0];
    const float* cosb      = (const float*)d_in[1];
    const float* sinb      = (const float*)d_in[2];
    const float* w_qa      = (const float*)d_in[3];
    const float* q_a_ln_w  = (const float*)d_in[4];
    const float* w_qb      = (const float*)d_in[5];
    const float* w_kva     = (const float*)d_in[6];
    const float* kv_a_ln_w = (const float*)d_in[7];
    const float* W_UK_T    = (const float*)d_in[8];
    const float* W_UV      = (const float*)d_in[9];
    const float* w_o       = (const float*)d_in[10];
    float* out = (float*)d_out;

    const int M = BB * SS;  // 2048
    // ---- HEAD region: transient buffers, later aliased by Sc (67.1 MB) ----
    float*  qakva = (float*)d_ws;
    __bf16* Xb    = (__bf16*)(qakva + (size_t)M * NCOMB);
    __bf16* qab   = Xb    + (size_t)M * HH;
    __bf16* qb    = qab   + (size_t)M * QLR;
    __bf16* qlatb = qb    + (size_t)M * NHD * QKD;   // slot kept (unused now)
    __bf16* Sc    = (__bf16*)d_ws;                    // aliases head after qlat
    // ---- TAIL region: persistent ----
    __bf16* Kc    = qlatb + (size_t)M * NHD * KVLR;   // M*576
    __bf16* Qc    = Kc    + (size_t)M * 576;          // M*9216
    __bf16* Vt    = Qc    + (size_t)M * NHD * 576;    // 2*512*1024 (unused R7)
    __bf16* ctxb  = Vt    + (size_t)BB * 512 * SS;    // M*8192: Vh lives here
    __bf16* Vh    = ctxb;                             // 32*128*1024 bf16 = 8MB
    __bf16* ohb   = ctxb  + (size_t)M * NHD * KVLR;   // M*2048
    __bf16* w_cmb = ohb   + (size_t)M * HH;           // 2176*2048
    __bf16* w_qbb = w_cmb + (size_t)NCOMB * HH;       // 3072*1536
    __bf16* Wkb   = w_qbb + (size_t)NHD * QKD * QLR;  // 16*512*128
    __bf16* Wvb   = Wkb   + (size_t)NHD * KVLR * NOPE;// 16*128*512
    __bf16* w_ob  = Wvb   + (size_t)NHD * VDIM * KVLR;// 2048*2048

    dim3 blk(256);

    // --- casts ---
    castf2b<<<dim3((M * HH) / 1024), blk, 0, stream>>>(hidden, Xb, M * HH);
    cast_comb<<<dim3((NCOMB * HH) / 1024), blk, 0, stream>>>(w_qa, w_kva, w_cmb);
    castf2b<<<dim3((NHD * QKD * QLR) / 1024), blk, 0, stream>>>(w_qb, w_qbb, NHD * QKD * QLR);
    castf2b<<<dim3((HH * HH) / 1024), blk, 0, stream>>>(w_o, w_ob, HH * HH);
    transpose_cast<<<dim3(KVLR / 32, NOPE / 32, NHD), blk, 0, stream>>>(W_UK_T, Wkb, NOPE, KVLR);
    transpose_cast<<<dim3(VDIM / 32, KVLR / 32, NHD), blk, 0, stream>>>(W_UV, Wvb, KVLR, VDIM);

    // 1+4 fused: qakva = Xb @ [w_qa; w_kva]^T   (2048 x 2176 x 2048)
    gemm_mfma<false, 64, 2, false><<<dim3(NCOMB / 128, M / 128, 1), blk, 0, stream>>>(
        Xb, w_cmb, qakva, M, NCOMB, HH, HH, HH, NCOMB, 0, 0, 0);
    // 2. qab = bf16(LN(qakva[:, :1536]))
    ln_kernel<<<dim3(M), blk, 0, stream>>>(qakva, q_a_ln_w, qab, QLR, NCOMB);
    // 3. qb = qab @ w_qb^T (bf16)              (2048 x 3072 x 1536)
    gemm_mfma<true, 64, 2, false><<<dim3(NHD * QKD / 128, M / 128, 1), blk, 0, stream>>>(
        qab, w_qbb, qb, M, NHD * QKD, QLR, QLR, QLR, NHD * QKD, 0, 0, 0);
    // 5. Kc = [LN(kv_c), rope(k_pe)] bf16; roped q_pe -> Qc[...,512:576)
    prep_kernel<<<dim3(M), blk, 0, stream>>>(qakva + QLR, NCOMB, kv_a_ln_w,
                                             cosb, sinb, Kc, qb, Qc);
    // 5b. Vh[z] = Wvb[h] @ Kc[b][:, :512]^T   (32 x [128 x 1024 x 512])
    gemm_vh<<<dim3(8, 1, 32), blk, 0, stream>>>(Wvb, Kc, Vh);
    // 6. Qc[...,0:512) = q_nope[h] @ Wkb[h]^T  (16 x [2048 x 512 x 128])
    gemm_qlat<<<dim3(KVLR / 128, M / 128, NHD), blk, 0, stream>>>(qb, Wkb, Qc);
    // 8a. Sc = causal scores, exact triangle grid (1152 blocks)
    gemm_scores<<<dim3(36, 32), blk, 0, stream>>>(Qc, Kc, Sc);
    // 8b. row softmax in place
    softmax_kernel<<<dim3(SS / 4, 32), blk, 0, stream>>>(Sc);
    // 8c. ohb = P @ Vh^T (head-space PV, causal k-bound)
    gemm_pv<<<dim3(8, 32), blk, 0, stream>>>(Sc, Vh, ohb);
    // 10. out = ohb @ w_o^T (fp32)             (2048 x 2048 x 2048)
    gemm_mfma<false, 64, 2, false><<<dim3(HH / 128, M / 128, 1), blk, 0, stream>>>(
        ohb, w_ob, out, M, HH, NHD * VDIM, NHD * VDIM, NHD * VDIM, HH, 0, 0, 0);
}